// Round 2
// 572.908 us; speedup vs baseline: 1.1520x; 1.1520x over previous
//
#include <hip/hip_runtime.h>
#include <hip/hip_bf16.h>

typedef unsigned short u16;
typedef short short8 __attribute__((ext_vector_type(8)));
typedef float f32x4 __attribute__((ext_vector_type(4)));

// Static device scratch: 13 x MELEM u16 slots.
#define MELEM 8388608u  // 8192*1024
__device__ u16 g_ws[(size_t)MELEM * 13];

__device__ __forceinline__ float b2f(u16 u) {
  union { unsigned int i; float f; } v; v.i = ((unsigned int)u) << 16; return v.f;
}
__device__ __forceinline__ u16 f2b(float f) {
  union { float f; unsigned int i; } v; v.f = f;
  return (u16)((v.i + 0x7FFFu + ((v.i >> 16) & 1u)) >> 16);  // RNE
}
__device__ __forceinline__ unsigned int pk2(float a, float b) {
  union { __hip_bfloat162 h; unsigned int u; } v;
  v.h = __float22bfloat162_rn(make_float2(a, b));  // v_cvt_pk_bf16_f32 (RNE)
  return v.u;
}
__device__ __forceinline__ f32x4 mfma16(short8 a, short8 b, f32x4 c) {
  return __builtin_amdgcn_mfma_f32_16x16x32_bf16(a, b, c, 0, 0, 0);
}

typedef __attribute__((address_space(3))) unsigned int lds_u32;
typedef const __attribute__((address_space(1))) unsigned int glb_u32;
__device__ __forceinline__ void gld16(u16* l, const u16* g) {
  __builtin_amdgcn_global_load_lds((glb_u32*)g, (lds_u32*)l, 16, 0, 0);
}

// ---- fp32 -> bf16 elementwise
__global__ __launch_bounds__(256) void convert_kernel(const float* __restrict__ src,
                                                      u16* __restrict__ dst, int n) {
  const int i = blockIdx.x * 256 + threadIdx.x;
  if (i < n) dst[i] = f2b(src[i]);
}

// ---- fp32 W(KxN) -> bf16 Wt(NxK) tiled transpose
__global__ __launch_bounds__(256) void transpose_kernel(const float* __restrict__ W,
                                                        u16* __restrict__ Wt,
                                                        int K, int N) {
  __shared__ float tile[32][33];
  const int bx = blockIdx.x * 32;
  const int by = blockIdx.y * 32;
  const int tx = threadIdx.x & 31, ty = threadIdx.x >> 5;
#pragma unroll
  for (int i = 0; i < 32; i += 8)
    tile[ty + i][tx] = W[(size_t)(by + ty + i) * N + bx + tx];
  __syncthreads();
#pragma unroll
  for (int i = 0; i < 32; i += 8)
    Wt[(size_t)(bx + ty + i) * K + by + tx] = f2b(tile[tx][ty + i]);
}

// ---- concat 3x1024 fp32 biases
__global__ __launch_bounds__(256) void concat3_kernel(const float* __restrict__ a,
                                                      const float* __restrict__ b,
                                                      const float* __restrict__ c,
                                                      float* __restrict__ o) {
  const int i = blockIdx.x * 256 + threadIdx.x;
  if (i < 1024) o[i] = a[i];
  else if (i < 2048) o[i] = b[i - 1024];
  else if (i < 3072) o[i] = c[i - 2048];
}

// ---------------- LayerNorm; fp32 in, bf16(+fp32) out
__global__ __launch_bounds__(256) void ln_kernel(const float* __restrict__ x,
                                                 const float* __restrict__ alpha,
                                                 const float* __restrict__ beta,
                                                 u16* __restrict__ outb,
                                                 float* __restrict__ outf) {
  const int D = 1024;
  const int row = blockIdx.x;
  const int tid = threadIdx.x;
  const float4 u = *(const float4*)(x + (size_t)row * D + tid * 4);
  float s1 = u.x + u.y + u.z + u.w;
  float s2 = u.x * u.x + u.y * u.y + u.z * u.z + u.w * u.w;
#pragma unroll
  for (int off = 32; off >= 1; off >>= 1) {
    s1 += __shfl_xor(s1, off, 64);
    s2 += __shfl_xor(s2, off, 64);
  }
  __shared__ float ws1[4], ws2[4];
  if ((tid & 63) == 0) { ws1[tid >> 6] = s1; ws2[tid >> 6] = s2; }
  __syncthreads();
  s1 = ws1[0] + ws1[1] + ws1[2] + ws1[3];
  s2 = ws2[0] + ws2[1] + ws2[2] + ws2[3];
  const float mean = s1 * (1.0f / 1024.0f);
  const float var = fmaxf((s2 - 1024.0f * mean * mean) * (1.0f / 1023.0f), 0.0f);
  const float inv = 1.0f / (sqrtf(var) + 1e-6f);
  const float4 a = *(const float4*)(alpha + tid * 4);
  const float4 b = *(const float4*)(beta + tid * 4);
  const float o0 = a.x * (u.x - mean) * inv + b.x;
  const float o1 = a.y * (u.y - mean) * inv + b.y;
  const float o2 = a.z * (u.z - mean) * inv + b.z;
  const float o3 = a.w * (u.w - mean) * inv + b.w;
  ushort4 ob; ob.x = f2b(o0); ob.y = f2b(o1); ob.z = f2b(o2); ob.w = f2b(o3);
  *(ushort4*)(outb + (size_t)row * D + tid * 4) = ob;
  if (outf) {
    float4 of; of.x = o0; of.y = o1; of.z = o2; of.w = o3;
    *(float4*)(outf + (size_t)row * D + tid * 4) = of;
  }
}

// ---------------- Templated MFMA GEMM: C = A(MxK) @ Bt(NxK)^T + bias [+resid] [relu]
// TMxTN tile, 4 waves, BK=32, global_load_lds width=16.
// TM=128: waves 2x2 of 64x64. TM=64: waves 1x4 of 64x(TN/4).
template<int TM, int TN>
__global__ __launch_bounds__(256) void gemm_t(
    const u16* __restrict__ A, const u16* __restrict__ A2,
    const u16* __restrict__ Bt, const float* __restrict__ bias,
    const float* __restrict__ resid, float* __restrict__ Cf, u16* __restrict__ Cb,
    int M, int N, int K, int K1, int relu) {
  __shared__ __align__(16) u16 As[TM * 32];
  __shared__ __align__(16) u16 Bs[TN * 32];
  const int tid = threadIdx.x;
  const int bn = blockIdx.x * TN;
  const int bm = blockIdx.y * TM;
  const int wv = tid >> 6, lane = tid & 63, quad = lane >> 4, l16 = lane & 15;
  constexpr int WN = (TM == 128) ? 64 : TN / 4;
  constexpr int AM = 4, AN = WN / 16;
  const int wm = (TM == 128) ? (wv >> 1) * 64 : 0;
  const int wn = (TM == 128) ? (wv & 1) * 64 : wv * WN;
  const int r0 = tid >> 2;
  const int cc = (tid & 3) * 8;
  f32x4 acc[AM][AN];
#pragma unroll
  for (int i = 0; i < AM; ++i)
#pragma unroll
    for (int j = 0; j < AN; ++j) acc[i][j] = (f32x4){0.f, 0.f, 0.f, 0.f};

  for (int k0 = 0; k0 < K; k0 += 32) {
    const u16* aS; int lda, kk;
    if (A2 != nullptr && k0 >= K1) { aS = A2; lda = K - K1; kk = k0 - K1; }
    else { aS = A; lda = (A2 != nullptr) ? K1 : K; kk = k0; }
#pragma unroll
    for (int i = 0; i < TM / 64; ++i)
      gld16(&As[i * 2048 + tid * 8], aS + (size_t)(bm + i * 64 + r0) * lda + kk + cc);
#pragma unroll
    for (int i = 0; i < TN / 64; ++i)
      gld16(&Bs[i * 2048 + tid * 8], Bt + (size_t)(bn + i * 64 + r0) * K + k0 + cc);
    __syncthreads();
    short8 af[AM], bf[AN];
#pragma unroll
    for (int mi = 0; mi < AM; ++mi)
      af[mi] = *(const short8*)&As[(wm + mi * 16 + l16) * 32 + quad * 8];
#pragma unroll
    for (int ni = 0; ni < AN; ++ni)
      bf[ni] = *(const short8*)&Bs[(wn + ni * 16 + l16) * 32 + quad * 8];
#pragma unroll
    for (int mi = 0; mi < AM; ++mi)
#pragma unroll
      for (int ni = 0; ni < AN; ++ni)
        acc[mi][ni] = mfma16(af[mi], bf[ni], acc[mi][ni]);
    __syncthreads();
  }

#pragma unroll
  for (int ni = 0; ni < AN; ++ni) {
    const int col = bn + wn + ni * 16 + l16;
    const float bb = bias ? bias[col] : 0.0f;
#pragma unroll
    for (int mi = 0; mi < AM; ++mi) {
#pragma unroll
      for (int r = 0; r < 4; ++r) {
        const int row = bm + wm + mi * 16 + quad * 4 + r;
        const size_t off = (size_t)row * N + col;
        float v = acc[mi][ni][r] + bb;
        if (resid) v += resid[off];
        if (relu) v = fmaxf(v, 0.0f);
        if (Cf) Cf[off] = v;
        if (Cb) Cb[off] = f2b(v);
      }
    }
  }
}

// ---------------- Flash attention, transposed orientation, single-barrier pipeline.
// 64-key double-buffered tiles; K staged via swizzled global_load_lds; V prefetched
// to regs, scattered post-compute. Fixed-reference softmax (clamp 60).
// Block = (b, h, 256 q rows) with 8 waves; wave = 32 q rows.
// Grid 512, XCD-swizzled so all 8 q-tiles of one (b,h) land on one XCD (K/V L2-resident).
__global__ __launch_bounds__(512) void attn_kernel(
    const u16* __restrict__ Q, const u16* __restrict__ Kb,
    const u16* __restrict__ Vb, u16* __restrict__ O, int ldq) {
  const int S = 2048, NT = 32;
  __shared__ __align__(16) u16 Ks[2][64][64];   // swizzled: chunk c stored at c^(key&7)
  __shared__ __align__(16) u16 Vt[2][64][72];   // [dh][key], +8 pad
  __shared__ __align__(16) u16 Pb[8][32][40];   // per-wave P^T: [qrow][key32]
  const int tid = threadIdx.x;
  // XCD-aware bijective swizzle: nwg=512, 8 XCDs, 64 blocks per XCD chunk.
  const int swz = ((blockIdx.x & 7) << 6) | (blockIdx.x >> 3);
  const int qt = swz & 7;
  const int bh = swz >> 3;
  const int b = bh >> 4, h = bh & 15;
  const int wv = tid >> 6, lane = tid & 63, quad = lane >> 4, l16 = lane & 15;
  const size_t brow = (size_t)b * S;
  const size_t hoff = (size_t)h * 64;
  const int q0 = qt * 256 + wv * 32;

  // Q B-frags [ni][ks], scaled by 0.125
  short8 qf[2][2];
#pragma unroll
  for (int ni = 0; ni < 2; ++ni)
#pragma unroll
    for (int ks = 0; ks < 2; ++ks) {
      int4 t = *(const int4*)(Q + (brow + q0 + ni * 16 + l16) * ldq + hoff + ks * 32 + quad * 8);
      const u16* p = (const u16*)&t;
      short8 f;
#pragma unroll
      for (int j = 0; j < 8; ++j) f[j] = (short)f2b(b2f(p[j]) * 0.125f);
      qf[ni][ks] = f;
    }

  f32x4 oacc[4][2];
#pragma unroll
  for (int mi = 0; mi < 4; ++mi)
#pragma unroll
    for (int ni = 0; ni < 2; ++ni) oacc[mi][ni] = (f32x4){0.f, 0.f, 0.f, 0.f};
  float lsum[2] = {0.0f, 0.0f};
  const f32x4 z4 = {0.f, 0.f, 0.f, 0.f};

  // ---- prologue: stage tile 0 into buffer 0 (512 threads = 512 chunks)
  {
    const int s = tid;
    const int key = s >> 3, c = (s & 7) ^ (key & 7);
    gld16(&Ks[0][0][0] + (size_t)s * 8, Kb + (brow + key) * ldq + hoff + c * 8);
    const int vkey = tid >> 3, c0 = (tid & 7) * 8;
    int4 vv = *(const int4*)(Vb + (brow + vkey) * ldq + hoff + c0);
    const u16* vp = (const u16*)&vv;
    const int rot = tid & 7;
#pragma unroll
    for (int j0 = 0; j0 < 8; ++j0) {
      const int j = (j0 + rot) & 7;
      Vt[0][c0 + j][vkey] = vp[j];
    }
  }
  __syncthreads();

  for (int t = 0; t < NT; ++t) {
    const int p = t & 1, np = p ^ 1;
    int4 va;
    if (t + 1 < NT) {
      const int kbn = (t + 1) * 64;
      const int s = tid;
      const int key = s >> 3, c = (s & 7) ^ (key & 7);
      gld16(&Ks[np][0][0] + (size_t)s * 8, Kb + (brow + kbn + key) * ldq + hoff + c * 8);
      const int vkey = tid >> 3, c0 = (tid & 7) * 8;
      va = *(const int4*)(Vb + (brow + kbn + vkey) * ldq + hoff + c0);
    }

    // ---- compute tile t from buffer p
    const u16* ksb = &Ks[p][0][0];
#pragma unroll
    for (int kk = 0; kk < 2; ++kk) {
#pragma unroll
      for (int half = 0; half < 2; ++half) {
        const int m = (kk * 2 + half) * 16 + l16;
        short8 af0 = *(const short8*)(ksb + m * 64 + ((quad ^ (m & 7)) * 8));
        short8 af1 = *(const short8*)(ksb + m * 64 + (((4 + quad) ^ (m & 7)) * 8));
#pragma unroll
        for (int ni = 0; ni < 2; ++ni) {
          f32x4 s = z4;
          s = mfma16(af0, qf[ni][0], s);
          s = mfma16(af1, qf[ni][1], s);
          const float e0 = __expf(fminf(s[0], 60.0f));
          const float e1 = __expf(fminf(s[1], 60.0f));
          const float e2 = __expf(fminf(s[2], 60.0f));
          const float e3 = __expf(fminf(s[3], 60.0f));
          lsum[ni] += (e0 + e1) + (e2 + e3);
          uint2 pk;
          pk.x = pk2(e0, e1);
          pk.y = pk2(e2, e3);
          *(uint2*)&Pb[wv][ni * 16 + l16][half * 16 + quad * 4] = pk;
        }
      }
      short8 pf[2];
#pragma unroll
      for (int ni = 0; ni < 2; ++ni)
        pf[ni] = *(const short8*)&Pb[wv][ni * 16 + l16][quad * 8];
      __builtin_amdgcn_s_setprio(1);
#pragma unroll
      for (int mi2 = 0; mi2 < 4; ++mi2) {
        short8 vf = *(const short8*)&Vt[p][mi2 * 16 + l16][kk * 32 + quad * 8];
#pragma unroll
        for (int ni = 0; ni < 2; ++ni)
          oacc[mi2][ni] = mfma16(vf, pf[ni], oacc[mi2][ni]);
      }
      __builtin_amdgcn_s_setprio(0);
    }

    if (t + 1 < NT) {
      const int vkey = tid >> 3, c0 = (tid & 7) * 8;
      const u16* vp = (const u16*)&va;
      const int rot = tid & 7;
#pragma unroll
      for (int j0 = 0; j0 < 8; ++j0) {
        const int j = (j0 + rot) & 7;
        Vt[np][c0 + j][vkey] = vp[j];
      }
      __syncthreads();
    }
  }

#pragma unroll
  for (int ni = 0; ni < 2; ++ni) {
    lsum[ni] += __shfl_xor(lsum[ni], 16, 64);
    lsum[ni] += __shfl_xor(lsum[ni], 32, 64);
  }
#pragma unroll
  for (int ni = 0; ni < 2; ++ni) {
    const float rl = 1.0f / lsum[ni];
    const size_t ob = (brow + q0 + ni * 16 + l16) * 1024 + hoff;
#pragma unroll
    for (int mi2 = 0; mi2 < 4; ++mi2) {
      uint2 ov;
      ov.x = pk2(oacc[mi2][ni][0] * rl, oacc[mi2][ni][1] * rl);
      ov.y = pk2(oacc[mi2][ni][2] * rl, oacc[mi2][ni][3] * rl);
      *(uint2*)(O + ob + mi2 * 16 + quad * 4) = ov;
    }
  }
}

extern "C" void kernel_launch(void* const* d_in, const int* in_sizes, int n_in,
                              void* d_out, int out_size, void* d_ws, size_t ws_size,
                              hipStream_t stream) {
  const int M = 8192, D = 1024, P = 256, DFF = 512;

  const float* feature_x = (const float*)d_in[0];
  const float* param_x   = (const float*)d_in[1];
  const float* Wq = (const float*)d_in[2];  const float* bq = (const float*)d_in[3];
  const float* Wk = (const float*)d_in[4];  const float* bk = (const float*)d_in[5];
  const float* Wv = (const float*)d_in[6];  const float* bv = (const float*)d_in[7];
  const float* Wo = (const float*)d_in[8];  const float* bo = (const float*)d_in[9];
  const float* alpha1 = (const float*)d_in[10]; const float* beta1 = (const float*)d_in[11];
  const float* alpha2 = (const float*)d_in[12]; const float* beta2 = (const float*)d_in[13];
  const float* W1 = (const float*)d_in[14]; const float* b1 = (const float*)d_in[15];
  const float* W2 = (const float*)d_in[16]; const float* b2 = (const float*)d_in[17];
  const float* Wp = (const float*)d_in[18]; const float* bp = (const float*)d_in[19];

  void* sym = nullptr;
  hipGetSymbolAddress(&sym, HIP_SYMBOL(g_ws));
  u16* s = (u16*)sym;

  u16* xn_b   = s + (size_t)MELEM * 0;
  float* xn_f = (float*)(s + (size_t)MELEM * 1);   // slots 1-2
  u16* qkv_b  = s + (size_t)MELEM * 3;             // slots 3-5 (M x 3072)
  u16* ctx    = s + (size_t)MELEM * 6;
  float* x1_f = (float*)(s + (size_t)MELEM * 7);   // slots 7-8
  u16* x2_b   = s + (size_t)MELEM * 9;
  u16* h1_b   = s + (size_t)MELEM * 10;            // M x 512
  u16* xcp_b  = s + (size_t)MELEM * 11;
  u16* wreg   = s + (size_t)MELEM * 12;
  u16* px_b   = wreg;                              // M x 256
  u16* Wqkvt  = px_b + 2097152;                    // 3072 x 1024
  u16* Wot    = Wqkvt + 3145728;                   // 1024 x 1024
  u16* W1t    = Wot + 1048576;                     // 512 x 1024
  u16* W2t    = W1t + 524288;                      // 1024 x 512
  u16* Wpt    = W2t + 524288;                      // 256 x 1280
  float* bqkv = (float*)(Wpt + 327680);            // 3072 fp32

  float* xout_f = (float*)d_out;
  float* pout_f = xout_f + (size_t)M * D;

  dim3 blk(256);
  // weight prep
  transpose_kernel<<<dim3(32, 32), blk, 0, stream>>>(Wq, Wqkvt, D, D);
  transpose_kernel<<<dim3(32, 32), blk, 0, stream>>>(Wk, Wqkvt + 1024 * 1024, D, D);
  transpose_kernel<<<dim3(32, 32), blk, 0, stream>>>(Wv, Wqkvt + 2048 * 1024, D, D);
  transpose_kernel<<<dim3(32, 32), blk, 0, stream>>>(Wo, Wot, D, D);
  transpose_kernel<<<dim3(16, 32), blk, 0, stream>>>(W1, W1t, D, DFF);
  transpose_kernel<<<dim3(32, 16), blk, 0, stream>>>(W2, W2t, DFF, D);
  transpose_kernel<<<dim3(8, 40), blk, 0, stream>>>(Wp, Wpt, D + P, P);
  concat3_kernel<<<12, blk, 0, stream>>>(bq, bk, bv, bqkv);
  convert_kernel<<<(M * P + 255) / 256, blk, 0, stream>>>(param_x, px_b, M * P);

  // pipeline
  ln_kernel<<<M, blk, 0, stream>>>(feature_x, alpha1, beta1, xn_b, xn_f);
  gemm_t<128, 128><<<dim3(24, 64), blk, 0, stream>>>(xn_b, nullptr, Wqkvt, bqkv, nullptr,
                                                     nullptr, qkv_b, M, 3072, D, D, 0);
  attn_kernel<<<512, dim3(512), 0, stream>>>(qkv_b, qkv_b + 1024, qkv_b + 2048, ctx, 3072);
  gemm_t<128, 128><<<dim3(8, 64), blk, 0, stream>>>(ctx, nullptr, Wot, bo, xn_f,
                                                    x1_f, nullptr, M, D, D, D, 0);
  ln_kernel<<<M, blk, 0, stream>>>(x1_f, alpha2, beta2, x2_b, nullptr);
  gemm_t<64, 128><<<dim3(4, 128), blk, 0, stream>>>(x2_b, nullptr, W1t, b1, nullptr,
                                                    nullptr, h1_b, M, DFF, D, D, 1);
  gemm_t<128, 128><<<dim3(8, 64), blk, 0, stream>>>(h1_b, nullptr, W2t, b2, x1_f,
                                                    xout_f, xcp_b, M, D, DFF, DFF, 0);
  gemm_t<64, 64><<<dim3(4, 128), blk, 0, stream>>>(xcp_b, px_b, Wpt, bp, nullptr,
                                                   pout_f, nullptr, M, P, D + P, D, 0);
}

// Round 3
// 566.268 us; speedup vs baseline: 1.1655x; 1.0117x over previous
//
#include <hip/hip_runtime.h>
#include <hip/hip_bf16.h>

typedef unsigned short u16;
typedef short short8 __attribute__((ext_vector_type(8)));
typedef float f32x4 __attribute__((ext_vector_type(4)));

// Static device scratch: 13 x MELEM u16 slots.
#define MELEM 8388608u  // 8192*1024
__device__ u16 g_ws[(size_t)MELEM * 13];

__device__ __forceinline__ float b2f(u16 u) {
  union { unsigned int i; float f; } v; v.i = ((unsigned int)u) << 16; return v.f;
}
__device__ __forceinline__ u16 f2b(float f) {
  union { float f; unsigned int i; } v; v.f = f;
  return (u16)((v.i + 0x7FFFu + ((v.i >> 16) & 1u)) >> 16);  // RNE
}
__device__ __forceinline__ unsigned int pk2(float a, float b) {
  union { __hip_bfloat162 h; unsigned int u; } v;
  v.h = __float22bfloat162_rn(make_float2(a, b));  // v_cvt_pk_bf16_f32 (RNE)
  return v.u;
}
__device__ __forceinline__ f32x4 mfma16(short8 a, short8 b, f32x4 c) {
  return __builtin_amdgcn_mfma_f32_16x16x32_bf16(a, b, c, 0, 0, 0);
}

typedef __attribute__((address_space(3))) unsigned int lds_u32;
typedef const __attribute__((address_space(1))) unsigned int glb_u32;
__device__ __forceinline__ void gld16(u16* l, const u16* g) {
  __builtin_amdgcn_global_load_lds((glb_u32*)g, (lds_u32*)l, 16, 0, 0);
}

// exp path: prefer direct exp2 (fold log2e into Q scale, saving one v_mul per score)
#if __has_builtin(__builtin_amdgcn_exp2f)
#define QSCALE 0.18033688011112042f   /* 0.125 * log2(e) */
#define SCLAMP 86.561714f             /* 60 * log2(e) */
#define FEXP(x) __builtin_amdgcn_exp2f(x)
#else
#define QSCALE 0.125f
#define SCLAMP 60.0f
#define FEXP(x) __expf(x)
#endif

// ---- fp32 -> bf16 elementwise
__global__ __launch_bounds__(256) void convert_kernel(const float* __restrict__ src,
                                                      u16* __restrict__ dst, int n) {
  const int i = blockIdx.x * 256 + threadIdx.x;
  if (i < n) dst[i] = f2b(src[i]);
}

// ---- fp32 W(KxN) -> bf16 Wt(NxK) tiled transpose
__global__ __launch_bounds__(256) void transpose_kernel(const float* __restrict__ W,
                                                        u16* __restrict__ Wt,
                                                        int K, int N) {
  __shared__ float tile[32][33];
  const int bx = blockIdx.x * 32;
  const int by = blockIdx.y * 32;
  const int tx = threadIdx.x & 31, ty = threadIdx.x >> 5;
#pragma unroll
  for (int i = 0; i < 32; i += 8)
    tile[ty + i][tx] = W[(size_t)(by + ty + i) * N + bx + tx];
  __syncthreads();
#pragma unroll
  for (int i = 0; i < 32; i += 8)
    Wt[(size_t)(bx + ty + i) * K + by + tx] = f2b(tile[tx][ty + i]);
}

// ---- concat 3x1024 fp32 biases
__global__ __launch_bounds__(256) void concat3_kernel(const float* __restrict__ a,
                                                      const float* __restrict__ b,
                                                      const float* __restrict__ c,
                                                      float* __restrict__ o) {
  const int i = blockIdx.x * 256 + threadIdx.x;
  if (i < 1024) o[i] = a[i];
  else if (i < 2048) o[i] = b[i - 1024];
  else if (i < 3072) o[i] = c[i - 2048];
}

// ---------------- LayerNorm; fp32 in, bf16(+fp32) out
__global__ __launch_bounds__(256) void ln_kernel(const float* __restrict__ x,
                                                 const float* __restrict__ alpha,
                                                 const float* __restrict__ beta,
                                                 u16* __restrict__ outb,
                                                 float* __restrict__ outf) {
  const int D = 1024;
  const int row = blockIdx.x;
  const int tid = threadIdx.x;
  const float4 u = *(const float4*)(x + (size_t)row * D + tid * 4);
  float s1 = u.x + u.y + u.z + u.w;
  float s2 = u.x * u.x + u.y * u.y + u.z * u.z + u.w * u.w;
#pragma unroll
  for (int off = 32; off >= 1; off >>= 1) {
    s1 += __shfl_xor(s1, off, 64);
    s2 += __shfl_xor(s2, off, 64);
  }
  __shared__ float ws1[4], ws2[4];
  if ((tid & 63) == 0) { ws1[tid >> 6] = s1; ws2[tid >> 6] = s2; }
  __syncthreads();
  s1 = ws1[0] + ws1[1] + ws1[2] + ws1[3];
  s2 = ws2[0] + ws2[1] + ws2[2] + ws2[3];
  const float mean = s1 * (1.0f / 1024.0f);
  const float var = fmaxf((s2 - 1024.0f * mean * mean) * (1.0f / 1023.0f), 0.0f);
  const float inv = 1.0f / (sqrtf(var) + 1e-6f);
  const float4 a = *(const float4*)(alpha + tid * 4);
  const float4 b = *(const float4*)(beta + tid * 4);
  const float o0 = a.x * (u.x - mean) * inv + b.x;
  const float o1 = a.y * (u.y - mean) * inv + b.y;
  const float o2 = a.z * (u.z - mean) * inv + b.z;
  const float o3 = a.w * (u.w - mean) * inv + b.w;
  ushort4 ob; ob.x = f2b(o0); ob.y = f2b(o1); ob.z = f2b(o2); ob.w = f2b(o3);
  *(ushort4*)(outb + (size_t)row * D + tid * 4) = ob;
  if (outf) {
    float4 of; of.x = o0; of.y = o1; of.z = o2; of.w = o3;
    *(float4*)(outf + (size_t)row * D + tid * 4) = of;
  }
}

// ---------------- Templated MFMA GEMM: C = A(MxK) @ Bt(NxK)^T + bias [+resid] [relu]
// TMxTN tile, 4 waves, BK=32, global_load_lds width=16.
// Single-barrier double-buffered pipeline (T3-minimum): stage(next) is issued
// before compute(cur); the one __syncthreads per K-step drains loads that had
// the whole previous compute phase in flight.
// TM=128: waves 2x2 of 64x64. TM=64: waves 1x4 of 64x(TN/4).
template<int TM, int TN>
__global__ __launch_bounds__(256) void gemm_t(
    const u16* __restrict__ A, const u16* __restrict__ A2,
    const u16* __restrict__ Bt, const float* __restrict__ bias,
    const float* __restrict__ resid, float* __restrict__ Cf, u16* __restrict__ Cb,
    int M, int N, int K, int K1, int relu) {
  __shared__ __align__(16) u16 As[2][TM * 32];
  __shared__ __align__(16) u16 Bs[2][TN * 32];
  const int tid = threadIdx.x;
  const int bn = blockIdx.x * TN;
  const int bm = blockIdx.y * TM;
  const int wv = tid >> 6, lane = tid & 63, quad = lane >> 4, l16 = lane & 15;
  constexpr int WN = (TM == 128) ? 64 : TN / 4;
  constexpr int AM = 4, AN = WN / 16;
  const int wm = (TM == 128) ? (wv >> 1) * 64 : 0;
  const int wn = (TM == 128) ? (wv & 1) * 64 : wv * WN;
  const int r0 = tid >> 2;
  const int cc = (tid & 3) * 8;
  f32x4 acc[AM][AN];
#pragma unroll
  for (int i = 0; i < AM; ++i)
#pragma unroll
    for (int j = 0; j < AN; ++j) acc[i][j] = (f32x4){0.f, 0.f, 0.f, 0.f};

  auto stage = [&](int buf, int k0) {
    const u16* aS; int lda, kk;
    if (A2 != nullptr && k0 >= K1) { aS = A2; lda = K - K1; kk = k0 - K1; }
    else { aS = A; lda = (A2 != nullptr) ? K1 : K; kk = k0; }
#pragma unroll
    for (int i = 0; i < TM / 64; ++i)
      gld16(&As[buf][i * 2048 + tid * 8], aS + (size_t)(bm + i * 64 + r0) * lda + kk + cc);
#pragma unroll
    for (int i = 0; i < TN / 64; ++i)
      gld16(&Bs[buf][i * 2048 + tid * 8], Bt + (size_t)(bn + i * 64 + r0) * K + k0 + cc);
  };

  const int nT = K >> 5;
  stage(0, 0);
  int cur = 0;
  for (int t = 0; t < nT; ++t) {
    __syncthreads();                      // buf[cur] DMA landed; prev reads done
    if (t + 1 < nT) stage(cur ^ 1, (t + 1) << 5);
    short8 af[AM], bf[AN];
#pragma unroll
    for (int mi = 0; mi < AM; ++mi)
      af[mi] = *(const short8*)&As[cur][(wm + mi * 16 + l16) * 32 + quad * 8];
#pragma unroll
    for (int ni = 0; ni < AN; ++ni)
      bf[ni] = *(const short8*)&Bs[cur][(wn + ni * 16 + l16) * 32 + quad * 8];
#pragma unroll
    for (int mi = 0; mi < AM; ++mi)
#pragma unroll
      for (int ni = 0; ni < AN; ++ni)
        acc[mi][ni] = mfma16(af[mi], bf[ni], acc[mi][ni]);
    cur ^= 1;
  }

#pragma unroll
  for (int ni = 0; ni < AN; ++ni) {
    const int col = bn + wn + ni * 16 + l16;
    const float bb = bias ? bias[col] : 0.0f;
#pragma unroll
    for (int mi = 0; mi < AM; ++mi) {
#pragma unroll
      for (int r = 0; r < 4; ++r) {
        const int row = bm + wm + mi * 16 + quad * 4 + r;
        const size_t off = (size_t)row * N + col;
        float v = acc[mi][ni][r] + bb;
        if (resid) v += resid[off];
        if (relu) v = fmaxf(v, 0.0f);
        if (Cf) Cf[off] = v;
        if (Cb) Cb[off] = f2b(v);
      }
    }
  }
}

// ---------------- Flash attention, transposed orientation, single-barrier pipeline.
// 64-key double-buffered tiles; K staged via swizzled global_load_lds; V prefetched
// to regs, scattered post-compute. Fixed-reference softmax (clamp), exp2-direct.
// Block = (b, h, 256 q rows) with 8 waves; wave = 32 q rows.
// Grid 512, XCD-swizzled so all 8 q-tiles of one (b,h) land on one XCD (K/V L2-resident).
__global__ __launch_bounds__(512) void attn_kernel(
    const u16* __restrict__ Q, const u16* __restrict__ Kb,
    const u16* __restrict__ Vb, u16* __restrict__ O, int ldq) {
  const int S = 2048, NT = 32;
  __shared__ __align__(16) u16 Ks[2][64][64];   // swizzled: chunk c stored at c^(key&7)
  __shared__ __align__(16) u16 Vt[2][64][72];   // [dh][key], +8 pad
  __shared__ __align__(16) u16 Pb[8][32][40];   // per-wave P^T: [qrow][key32]
  const int tid = threadIdx.x;
  // XCD-aware bijective swizzle: nwg=512, 8 XCDs, 64 blocks per XCD chunk.
  const int swz = ((blockIdx.x & 7) << 6) | (blockIdx.x >> 3);
  const int qt = swz & 7;
  const int bh = swz >> 3;
  const int b = bh >> 4, h = bh & 15;
  const int wv = tid >> 6, lane = tid & 63, quad = lane >> 4, l16 = lane & 15;
  const size_t brow = (size_t)b * S;
  const size_t hoff = (size_t)h * 64;
  const int q0 = qt * 256 + wv * 32;

  // Q B-frags [ni][ks], scaled by QSCALE
  short8 qf[2][2];
#pragma unroll
  for (int ni = 0; ni < 2; ++ni)
#pragma unroll
    for (int ks = 0; ks < 2; ++ks) {
      int4 t = *(const int4*)(Q + (brow + q0 + ni * 16 + l16) * ldq + hoff + ks * 32 + quad * 8);
      const u16* p = (const u16*)&t;
      short8 f;
#pragma unroll
      for (int j = 0; j < 8; ++j) f[j] = (short)f2b(b2f(p[j]) * QSCALE);
      qf[ni][ks] = f;
    }

  f32x4 oacc[4][2];
#pragma unroll
  for (int mi = 0; mi < 4; ++mi)
#pragma unroll
    for (int ni = 0; ni < 2; ++ni) oacc[mi][ni] = (f32x4){0.f, 0.f, 0.f, 0.f};
  float lsum[2] = {0.0f, 0.0f};
  const f32x4 z4 = {0.f, 0.f, 0.f, 0.f};

  // ---- prologue: stage tile 0 into buffer 0 (512 threads = 512 chunks)
  {
    const int s = tid;
    const int key = s >> 3, c = (s & 7) ^ (key & 7);
    gld16(&Ks[0][0][0] + (size_t)s * 8, Kb + (brow + key) * ldq + hoff + c * 8);
    const int vkey = tid >> 3, c0 = (tid & 7) * 8;
    int4 vv = *(const int4*)(Vb + (brow + vkey) * ldq + hoff + c0);
    const u16* vp = (const u16*)&vv;
    const int rot = tid & 7;
#pragma unroll
    for (int j0 = 0; j0 < 8; ++j0) {
      const int j = (j0 + rot) & 7;
      Vt[0][c0 + j][vkey] = vp[j];
    }
  }
  __syncthreads();

  for (int t = 0; t < NT; ++t) {
    const int p = t & 1, np = p ^ 1;
    int4 va;
    if (t + 1 < NT) {
      const int kbn = (t + 1) * 64;
      const int s = tid;
      const int key = s >> 3, c = (s & 7) ^ (key & 7);
      gld16(&Ks[np][0][0] + (size_t)s * 8, Kb + (brow + kbn + key) * ldq + hoff + c * 8);
      const int vkey = tid >> 3, c0 = (tid & 7) * 8;
      va = *(const int4*)(Vb + (brow + kbn + vkey) * ldq + hoff + c0);
    }

    // ---- compute tile t from buffer p
    const u16* ksb = &Ks[p][0][0];
#pragma unroll
    for (int kk = 0; kk < 2; ++kk) {
#pragma unroll
      for (int half = 0; half < 2; ++half) {
        const int m = (kk * 2 + half) * 16 + l16;
        short8 af0 = *(const short8*)(ksb + m * 64 + ((quad ^ (m & 7)) * 8));
        short8 af1 = *(const short8*)(ksb + m * 64 + (((4 + quad) ^ (m & 7)) * 8));
#pragma unroll
        for (int ni = 0; ni < 2; ++ni) {
          f32x4 s = z4;
          s = mfma16(af0, qf[ni][0], s);
          s = mfma16(af1, qf[ni][1], s);
          const float e0 = FEXP(fminf(s[0], SCLAMP));
          const float e1 = FEXP(fminf(s[1], SCLAMP));
          const float e2 = FEXP(fminf(s[2], SCLAMP));
          const float e3 = FEXP(fminf(s[3], SCLAMP));
          lsum[ni] += (e0 + e1) + (e2 + e3);
          uint2 pk;
          pk.x = pk2(e0, e1);
          pk.y = pk2(e2, e3);
          *(uint2*)&Pb[wv][ni * 16 + l16][half * 16 + quad * 4] = pk;
        }
      }
      short8 pf[2];
#pragma unroll
      for (int ni = 0; ni < 2; ++ni)
        pf[ni] = *(const short8*)&Pb[wv][ni * 16 + l16][quad * 8];
      __builtin_amdgcn_s_setprio(1);
#pragma unroll
      for (int mi2 = 0; mi2 < 4; ++mi2) {
        short8 vf = *(const short8*)&Vt[p][mi2 * 16 + l16][kk * 32 + quad * 8];
#pragma unroll
        for (int ni = 0; ni < 2; ++ni)
          oacc[mi2][ni] = mfma16(vf, pf[ni], oacc[mi2][ni]);
      }
      __builtin_amdgcn_s_setprio(0);
    }

    if (t + 1 < NT) {
      const int vkey = tid >> 3, c0 = (tid & 7) * 8;
      const u16* vp = (const u16*)&va;
      const int rot = tid & 7;
#pragma unroll
      for (int j0 = 0; j0 < 8; ++j0) {
        const int j = (j0 + rot) & 7;
        Vt[np][c0 + j][vkey] = vp[j];
      }
      __syncthreads();
    }
  }

#pragma unroll
  for (int ni = 0; ni < 2; ++ni) {
    lsum[ni] += __shfl_xor(lsum[ni], 16, 64);
    lsum[ni] += __shfl_xor(lsum[ni], 32, 64);
  }
#pragma unroll
  for (int ni = 0; ni < 2; ++ni) {
    const float rl = 1.0f / lsum[ni];
    const size_t ob = (brow + q0 + ni * 16 + l16) * 1024 + hoff;
#pragma unroll
    for (int mi2 = 0; mi2 < 4; ++mi2) {
      uint2 ov;
      ov.x = pk2(oacc[mi2][ni][0] * rl, oacc[mi2][ni][1] * rl);
      ov.y = pk2(oacc[mi2][ni][2] * rl, oacc[mi2][ni][3] * rl);
      *(uint2*)(O + ob + mi2 * 16 + quad * 4) = ov;
    }
  }
}

extern "C" void kernel_launch(void* const* d_in, const int* in_sizes, int n_in,
                              void* d_out, int out_size, void* d_ws, size_t ws_size,
                              hipStream_t stream) {
  const int M = 8192, D = 1024, P = 256, DFF = 512;

  const float* feature_x = (const float*)d_in[0];
  const float* param_x   = (const float*)d_in[1];
  const float* Wq = (const float*)d_in[2];  const float* bq = (const float*)d_in[3];
  const float* Wk = (const float*)d_in[4];  const float* bk = (const float*)d_in[5];
  const float* Wv = (const float*)d_in[6];  const float* bv = (const float*)d_in[7];
  const float* Wo = (const float*)d_in[8];  const float* bo = (const float*)d_in[9];
  const float* alpha1 = (const float*)d_in[10]; const float* beta1 = (const float*)d_in[11];
  const float* alpha2 = (const float*)d_in[12]; const float* beta2 = (const float*)d_in[13];
  const float* W1 = (const float*)d_in[14]; const float* b1 = (const float*)d_in[15];
  const float* W2 = (const float*)d_in[16]; const float* b2 = (const float*)d_in[17];
  const float* Wp = (const float*)d_in[18]; const float* bp = (const float*)d_in[19];

  void* sym = nullptr;
  hipGetSymbolAddress(&sym, HIP_SYMBOL(g_ws));
  u16* s = (u16*)sym;

  u16* xn_b   = s + (size_t)MELEM * 0;
  float* xn_f = (float*)(s + (size_t)MELEM * 1);   // slots 1-2
  u16* qkv_b  = s + (size_t)MELEM * 3;             // slots 3-5 (M x 3072)
  u16* ctx    = s + (size_t)MELEM * 6;
  float* x1_f = (float*)(s + (size_t)MELEM * 7);   // slots 7-8
  u16* x2_b   = s + (size_t)MELEM * 9;
  u16* h1_b   = s + (size_t)MELEM * 10;            // M x 512
  u16* xcp_b  = s + (size_t)MELEM * 11;
  u16* wreg   = s + (size_t)MELEM * 12;
  u16* px_b   = wreg;                              // M x 256
  u16* Wqkvt  = px_b + 2097152;                    // 3072 x 1024
  u16* Wot    = Wqkvt + 3145728;                   // 1024 x 1024
  u16* W1t    = Wot + 1048576;                     // 512 x 1024
  u16* W2t    = W1t + 524288;                      // 1024 x 512
  u16* Wpt    = W2t + 524288;                      // 256 x 1280
  float* bqkv = (float*)(Wpt + 327680);            // 3072 fp32

  float* xout_f = (float*)d_out;
  float* pout_f = xout_f + (size_t)M * D;

  dim3 blk(256);
  // weight prep
  transpose_kernel<<<dim3(32, 32), blk, 0, stream>>>(Wq, Wqkvt, D, D);
  transpose_kernel<<<dim3(32, 32), blk, 0, stream>>>(Wk, Wqkvt + 1024 * 1024, D, D);
  transpose_kernel<<<dim3(32, 32), blk, 0, stream>>>(Wv, Wqkvt + 2048 * 1024, D, D);
  transpose_kernel<<<dim3(32, 32), blk, 0, stream>>>(Wo, Wot, D, D);
  transpose_kernel<<<dim3(16, 32), blk, 0, stream>>>(W1, W1t, D, DFF);
  transpose_kernel<<<dim3(32, 16), blk, 0, stream>>>(W2, W2t, DFF, D);
  transpose_kernel<<<dim3(8, 40), blk, 0, stream>>>(Wp, Wpt, D + P, P);
  concat3_kernel<<<12, blk, 0, stream>>>(bq, bk, bv, bqkv);
  convert_kernel<<<(M * P + 255) / 256, blk, 0, stream>>>(param_x, px_b, M * P);

  // pipeline
  ln_kernel<<<M, blk, 0, stream>>>(feature_x, alpha1, beta1, xn_b, xn_f);
  gemm_t<128, 128><<<dim3(24, 64), blk, 0, stream>>>(xn_b, nullptr, Wqkvt, bqkv, nullptr,
                                                     nullptr, qkv_b, M, 3072, D, D, 0);
  attn_kernel<<<512, dim3(512), 0, stream>>>(qkv_b, qkv_b + 1024, qkv_b + 2048, ctx, 3072);
  gemm_t<128, 128><<<dim3(8, 64), blk, 0, stream>>>(ctx, nullptr, Wot, bo, xn_f,
                                                    x1_f, nullptr, M, D, D, D, 0);
  ln_kernel<<<M, blk, 0, stream>>>(x1_f, alpha2, beta2, x2_b, nullptr);
  gemm_t<64, 128><<<dim3(4, 128), blk, 0, stream>>>(x2_b, nullptr, W1t, b1, nullptr,
                                                    nullptr, h1_b, M, DFF, D, D, 1);
  gemm_t<128, 128><<<dim3(8, 64), blk, 0, stream>>>(h1_b, nullptr, W2t, b2, x1_f,
                                                    xout_f, xcp_b, M, D, DFF, DFF, 0);
  gemm_t<64, 64><<<dim3(4, 128), blk, 0, stream>>>(xcp_b, px_b, Wpt, bp, nullptr,
                                                   pout_f, nullptr, M, P, D + P, D, 0);
}

// Round 4
// 565.147 us; speedup vs baseline: 1.1679x; 1.0020x over previous
//
#include <hip/hip_runtime.h>
#include <hip/hip_bf16.h>

typedef unsigned short u16;
typedef short short8 __attribute__((ext_vector_type(8)));
typedef float f32x4 __attribute__((ext_vector_type(4)));

// Static device scratch: 13 x MELEM u16 slots.
#define MELEM 8388608u  // 8192*1024
__device__ u16 g_ws[(size_t)MELEM * 13];

__device__ __forceinline__ float b2f(u16 u) {
  union { unsigned int i; float f; } v; v.i = ((unsigned int)u) << 16; return v.f;
}
__device__ __forceinline__ u16 f2b(float f) {
  union { float f; unsigned int i; } v; v.f = f;
  return (u16)((v.i + 0x7FFFu + ((v.i >> 16) & 1u)) >> 16);  // RNE
}
__device__ __forceinline__ unsigned int pk2(float a, float b) {
  union { __hip_bfloat162 h; unsigned int u; } v;
  v.h = __float22bfloat162_rn(make_float2(a, b));  // v_cvt_pk_bf16_f32 (RNE)
  return v.u;
}
__device__ __forceinline__ f32x4 mfma16(short8 a, short8 b, f32x4 c) {
  return __builtin_amdgcn_mfma_f32_16x16x32_bf16(a, b, c, 0, 0, 0);
}

typedef __attribute__((address_space(3))) unsigned int lds_u32;
typedef const __attribute__((address_space(1))) unsigned int glb_u32;
__device__ __forceinline__ void gld16(u16* l, const u16* g) {
  __builtin_amdgcn_global_load_lds((glb_u32*)g, (lds_u32*)l, 16, 0, 0);
}

// exp path: prefer direct exp2 (fold log2e into Q scale, saving one v_mul per score)
#if __has_builtin(__builtin_amdgcn_exp2f)
#define QSCALE 0.18033688011112042f   /* 0.125 * log2(e) */
#define SCLAMP 86.561714f             /* 60 * log2(e) */
#define FEXP(x) __builtin_amdgcn_exp2f(x)
#else
#define QSCALE 0.125f
#define SCLAMP 60.0f
#define FEXP(x) __expf(x)
#endif

// ---- 32x32 fp32->bf16 transpose tile body (shared by all prep transpose jobs)
__device__ __forceinline__ void tr32(const float* __restrict__ W, u16* __restrict__ Wt,
                                     int K, int N, int bx, int by, int tid,
                                     float (*tile)[33]) {
  const int tx = tid & 31, ty = tid >> 5;
#pragma unroll
  for (int i = 0; i < 32; i += 8)
    tile[ty + i][tx] = W[(size_t)(by + ty + i) * N + bx + tx];
  __syncthreads();
#pragma unroll
  for (int i = 0; i < 32; i += 8)
    Wt[(size_t)(bx + ty + i) * K + by + tx] = f2b(tile[tx][ty + i]);
}

// ---- Fused weight prep: 7 transposes + bias concat + param_x convert in ONE launch.
// Flattened grid; job selected by block-uniform range checks.
//   [0,4096)      4x DxD transposes (Wq,Wk,Wv->Wqkvt slices, Wo->Wot), 1024 blocks each
//   [4096,4608)   W1  (K=1024,N=512)  grid 16x32
//   [4608,5120)   W2  (K=512, N=1024) grid 32x16
//   [5120,5440)   Wp  (K=1280,N=256)  grid 8x40
//   [5440,5452)   bias concat (3072 elems)
//   [5452,13644)  param_x fp32->bf16 (2097152 elems)
__global__ __launch_bounds__(256) void prep_kernel(
    const float* __restrict__ Wq, const float* __restrict__ Wk,
    const float* __restrict__ Wv, const float* __restrict__ Wo,
    const float* __restrict__ W1, const float* __restrict__ W2,
    const float* __restrict__ Wp,
    const float* __restrict__ bq, const float* __restrict__ bk,
    const float* __restrict__ bv, const float* __restrict__ param_x,
    u16* __restrict__ Wqkvt, u16* __restrict__ Wot, u16* __restrict__ W1t,
    u16* __restrict__ W2t, u16* __restrict__ Wpt,
    float* __restrict__ bqkv, u16* __restrict__ px_b) {
  __shared__ float tile[32][33];
  const int bid = blockIdx.x;
  const int tid = threadIdx.x;
  if (bid < 4096) {
    const int j = bid >> 10, r = bid & 1023;
    const int bx = (r & 31) * 32, by = (r >> 5) * 32;
    const float* src = (j == 0) ? Wq : (j == 1) ? Wk : (j == 2) ? Wv : Wo;
    u16* dst = (j == 3) ? Wot : (Wqkvt + (size_t)j * 1024 * 1024);
    tr32(src, dst, 1024, 1024, bx, by, tid, tile);
  } else if (bid < 4608) {
    const int r = bid - 4096;
    tr32(W1, W1t, 1024, 512, (r & 15) * 32, (r >> 4) * 32, tid, tile);
  } else if (bid < 5120) {
    const int r = bid - 4608;
    tr32(W2, W2t, 512, 1024, (r & 31) * 32, (r >> 5) * 32, tid, tile);
  } else if (bid < 5440) {
    const int r = bid - 5120;
    tr32(Wp, Wpt, 1280, 256, (r & 7) * 32, (r >> 3) * 32, tid, tile);
  } else if (bid < 5452) {
    const int i = (bid - 5440) * 256 + tid;
    bqkv[i] = (i < 1024) ? bq[i] : (i < 2048) ? bk[i - 1024] : bv[i - 2048];
  } else {
    const int i = (bid - 5452) * 256 + tid;
    px_b[i] = f2b(param_x[i]);
  }
}

// ---------------- LayerNorm; fp32 in, bf16(+fp32) out
__global__ __launch_bounds__(256) void ln_kernel(const float* __restrict__ x,
                                                 const float* __restrict__ alpha,
                                                 const float* __restrict__ beta,
                                                 u16* __restrict__ outb,
                                                 float* __restrict__ outf) {
  const int D = 1024;
  const int row = blockIdx.x;
  const int tid = threadIdx.x;
  const float4 u = *(const float4*)(x + (size_t)row * D + tid * 4);
  float s1 = u.x + u.y + u.z + u.w;
  float s2 = u.x * u.x + u.y * u.y + u.z * u.z + u.w * u.w;
#pragma unroll
  for (int off = 32; off >= 1; off >>= 1) {
    s1 += __shfl_xor(s1, off, 64);
    s2 += __shfl_xor(s2, off, 64);
  }
  __shared__ float ws1[4], ws2[4];
  if ((tid & 63) == 0) { ws1[tid >> 6] = s1; ws2[tid >> 6] = s2; }
  __syncthreads();
  s1 = ws1[0] + ws1[1] + ws1[2] + ws1[3];
  s2 = ws2[0] + ws2[1] + ws2[2] + ws2[3];
  const float mean = s1 * (1.0f / 1024.0f);
  const float var = fmaxf((s2 - 1024.0f * mean * mean) * (1.0f / 1023.0f), 0.0f);
  const float inv = 1.0f / (sqrtf(var) + 1e-6f);
  const float4 a = *(const float4*)(alpha + tid * 4);
  const float4 b = *(const float4*)(beta + tid * 4);
  const float o0 = a.x * (u.x - mean) * inv + b.x;
  const float o1 = a.y * (u.y - mean) * inv + b.y;
  const float o2 = a.z * (u.z - mean) * inv + b.z;
  const float o3 = a.w * (u.w - mean) * inv + b.w;
  ushort4 ob; ob.x = f2b(o0); ob.y = f2b(o1); ob.z = f2b(o2); ob.w = f2b(o3);
  *(ushort4*)(outb + (size_t)row * D + tid * 4) = ob;
  if (outf) {
    float4 of; of.x = o0; of.y = o1; of.z = o2; of.w = o3;
    *(float4*)(outf + (size_t)row * D + tid * 4) = of;
  }
}

// ---------------- Templated MFMA GEMM: C = A(MxK) @ Bt(NxK)^T + bias [+resid] [relu]
// TMxTN tile, 4 waves, BK=32, global_load_lds width=16. Single-buffer 2-barrier
// (proven round-2 structure; dbuf was measured null-to-negative here).
// TM=128: waves 2x2 of 64x64. TM=64: waves 1x4 of 64x(TN/4).
template<int TM, int TN>
__global__ __launch_bounds__(256) void gemm_t(
    const u16* __restrict__ A, const u16* __restrict__ A2,
    const u16* __restrict__ Bt, const float* __restrict__ bias,
    const float* __restrict__ resid, float* __restrict__ Cf, u16* __restrict__ Cb,
    int M, int N, int K, int K1, int relu) {
  __shared__ __align__(16) u16 As[TM * 32];
  __shared__ __align__(16) u16 Bs[TN * 32];
  const int tid = threadIdx.x;
  const int bn = blockIdx.x * TN;
  const int bm = blockIdx.y * TM;
  const int wv = tid >> 6, lane = tid & 63, quad = lane >> 4, l16 = lane & 15;
  constexpr int WN = (TM == 128) ? 64 : TN / 4;
  constexpr int AM = 4, AN = WN / 16;
  const int wm = (TM == 128) ? (wv >> 1) * 64 : 0;
  const int wn = (TM == 128) ? (wv & 1) * 64 : wv * WN;
  const int r0 = tid >> 2;
  const int cc = (tid & 3) * 8;
  f32x4 acc[AM][AN];
#pragma unroll
  for (int i = 0; i < AM; ++i)
#pragma unroll
    for (int j = 0; j < AN; ++j) acc[i][j] = (f32x4){0.f, 0.f, 0.f, 0.f};

  for (int k0 = 0; k0 < K; k0 += 32) {
    const u16* aS; int lda, kk;
    if (A2 != nullptr && k0 >= K1) { aS = A2; lda = K - K1; kk = k0 - K1; }
    else { aS = A; lda = (A2 != nullptr) ? K1 : K; kk = k0; }
#pragma unroll
    for (int i = 0; i < TM / 64; ++i)
      gld16(&As[i * 2048 + tid * 8], aS + (size_t)(bm + i * 64 + r0) * lda + kk + cc);
#pragma unroll
    for (int i = 0; i < TN / 64; ++i)
      gld16(&Bs[i * 2048 + tid * 8], Bt + (size_t)(bn + i * 64 + r0) * K + k0 + cc);
    __syncthreads();
    short8 af[AM], bf[AN];
#pragma unroll
    for (int mi = 0; mi < AM; ++mi)
      af[mi] = *(const short8*)&As[(wm + mi * 16 + l16) * 32 + quad * 8];
#pragma unroll
    for (int ni = 0; ni < AN; ++ni)
      bf[ni] = *(const short8*)&Bs[(wn + ni * 16 + l16) * 32 + quad * 8];
#pragma unroll
    for (int mi = 0; mi < AM; ++mi)
#pragma unroll
      for (int ni = 0; ni < AN; ++ni)
        acc[mi][ni] = mfma16(af[mi], bf[ni], acc[mi][ni]);
    __syncthreads();
  }

#pragma unroll
  for (int ni = 0; ni < AN; ++ni) {
    const int col = bn + wn + ni * 16 + l16;
    const float bb = bias ? bias[col] : 0.0f;
#pragma unroll
    for (int mi = 0; mi < AM; ++mi) {
#pragma unroll
      for (int r = 0; r < 4; ++r) {
        const int row = bm + wm + mi * 16 + quad * 4 + r;
        const size_t off = (size_t)row * N + col;
        float v = acc[mi][ni][r] + bb;
        if (resid) v += resid[off];
        if (relu) v = fmaxf(v, 0.0f);
        if (Cf) Cf[off] = v;
        if (Cb) Cb[off] = f2b(v);
      }
    }
  }
}

// ---------------- Flash attention, transposed orientation, single-barrier pipeline.
// 64-key double-buffered tiles; K staged via swizzled global_load_lds; V prefetched
// to regs, scattered post-compute. Fixed-reference softmax (clamp), exp2-direct.
// Block = (b, h, 256 q rows) with 8 waves; wave = 32 q rows.
// Grid 512, XCD-swizzled so all 8 q-tiles of one (b,h) land on one XCD (K/V L2-resident).
__global__ __launch_bounds__(512) void attn_kernel(
    const u16* __restrict__ Q, const u16* __restrict__ Kb,
    const u16* __restrict__ Vb, u16* __restrict__ O, int ldq) {
  const int S = 2048, NT = 32;
  __shared__ __align__(16) u16 Ks[2][64][64];   // swizzled: chunk c stored at c^(key&7)
  __shared__ __align__(16) u16 Vt[2][64][72];   // [dh][key], +8 pad
  __shared__ __align__(16) u16 Pb[8][32][40];   // per-wave P^T: [qrow][key32]
  const int tid = threadIdx.x;
  // XCD-aware bijective swizzle: nwg=512, 8 XCDs, 64 blocks per XCD chunk.
  const int swz = ((blockIdx.x & 7) << 6) | (blockIdx.x >> 3);
  const int qt = swz & 7;
  const int bh = swz >> 3;
  const int b = bh >> 4, h = bh & 15;
  const int wv = tid >> 6, lane = tid & 63, quad = lane >> 4, l16 = lane & 15;
  const size_t brow = (size_t)b * S;
  const size_t hoff = (size_t)h * 64;
  const int q0 = qt * 256 + wv * 32;

  // Q B-frags [ni][ks], scaled by QSCALE
  short8 qf[2][2];
#pragma unroll
  for (int ni = 0; ni < 2; ++ni)
#pragma unroll
    for (int ks = 0; ks < 2; ++ks) {
      int4 t = *(const int4*)(Q + (brow + q0 + ni * 16 + l16) * ldq + hoff + ks * 32 + quad * 8);
      const u16* p = (const u16*)&t;
      short8 f;
#pragma unroll
      for (int j = 0; j < 8; ++j) f[j] = (short)f2b(b2f(p[j]) * QSCALE);
      qf[ni][ks] = f;
    }

  f32x4 oacc[4][2];
#pragma unroll
  for (int mi = 0; mi < 4; ++mi)
#pragma unroll
    for (int ni = 0; ni < 2; ++ni) oacc[mi][ni] = (f32x4){0.f, 0.f, 0.f, 0.f};
  float lsum[2] = {0.0f, 0.0f};
  const f32x4 z4 = {0.f, 0.f, 0.f, 0.f};

  // ---- prologue: stage tile 0 into buffer 0 (512 threads = 512 chunks)
  {
    const int s = tid;
    const int key = s >> 3, c = (s & 7) ^ (key & 7);
    gld16(&Ks[0][0][0] + (size_t)s * 8, Kb + (brow + key) * ldq + hoff + c * 8);
    const int vkey = tid >> 3, c0 = (tid & 7) * 8;
    int4 vv = *(const int4*)(Vb + (brow + vkey) * ldq + hoff + c0);
    const u16* vp = (const u16*)&vv;
    const int rot = tid & 7;
#pragma unroll
    for (int j0 = 0; j0 < 8; ++j0) {
      const int j = (j0 + rot) & 7;
      Vt[0][c0 + j][vkey] = vp[j];
    }
  }
  __syncthreads();

  for (int t = 0; t < NT; ++t) {
    const int p = t & 1, np = p ^ 1;
    int4 va;
    if (t + 1 < NT) {
      const int kbn = (t + 1) * 64;
      const int s = tid;
      const int key = s >> 3, c = (s & 7) ^ (key & 7);
      gld16(&Ks[np][0][0] + (size_t)s * 8, Kb + (brow + kbn + key) * ldq + hoff + c * 8);
      const int vkey = tid >> 3, c0 = (tid & 7) * 8;
      va = *(const int4*)(Vb + (brow + kbn + vkey) * ldq + hoff + c0);
    }

    // ---- compute tile t from buffer p
    const u16* ksb = &Ks[p][0][0];
#pragma unroll
    for (int kk = 0; kk < 2; ++kk) {
#pragma unroll
      for (int half = 0; half < 2; ++half) {
        const int m = (kk * 2 + half) * 16 + l16;
        short8 af0 = *(const short8*)(ksb + m * 64 + ((quad ^ (m & 7)) * 8));
        short8 af1 = *(const short8*)(ksb + m * 64 + (((4 + quad) ^ (m & 7)) * 8));
#pragma unroll
        for (int ni = 0; ni < 2; ++ni) {
          f32x4 s = z4;
          s = mfma16(af0, qf[ni][0], s);
          s = mfma16(af1, qf[ni][1], s);
          const float e0 = FEXP(fminf(s[0], SCLAMP));
          const float e1 = FEXP(fminf(s[1], SCLAMP));
          const float e2 = FEXP(fminf(s[2], SCLAMP));
          const float e3 = FEXP(fminf(s[3], SCLAMP));
          lsum[ni] += (e0 + e1) + (e2 + e3);
          uint2 pk;
          pk.x = pk2(e0, e1);
          pk.y = pk2(e2, e3);
          *(uint2*)&Pb[wv][ni * 16 + l16][half * 16 + quad * 4] = pk;
        }
      }
      short8 pf[2];
#pragma unroll
      for (int ni = 0; ni < 2; ++ni)
        pf[ni] = *(const short8*)&Pb[wv][ni * 16 + l16][quad * 8];
      __builtin_amdgcn_s_setprio(1);
#pragma unroll
      for (int mi2 = 0; mi2 < 4; ++mi2) {
        short8 vf = *(const short8*)&Vt[p][mi2 * 16 + l16][kk * 32 + quad * 8];
#pragma unroll
        for (int ni = 0; ni < 2; ++ni)
          oacc[mi2][ni] = mfma16(vf, pf[ni], oacc[mi2][ni]);
      }
      __builtin_amdgcn_s_setprio(0);
    }

    if (t + 1 < NT) {
      const int vkey = tid >> 3, c0 = (tid & 7) * 8;
      const u16* vp = (const u16*)&va;
      const int rot = tid & 7;
#pragma unroll
      for (int j0 = 0; j0 < 8; ++j0) {
        const int j = (j0 + rot) & 7;
        Vt[np][c0 + j][vkey] = vp[j];
      }
      __syncthreads();
    }
  }

#pragma unroll
  for (int ni = 0; ni < 2; ++ni) {
    lsum[ni] += __shfl_xor(lsum[ni], 16, 64);
    lsum[ni] += __shfl_xor(lsum[ni], 32, 64);
  }
#pragma unroll
  for (int ni = 0; ni < 2; ++ni) {
    const float rl = 1.0f / lsum[ni];
    const size_t ob = (brow + q0 + ni * 16 + l16) * 1024 + hoff;
#pragma unroll
    for (int mi2 = 0; mi2 < 4; ++mi2) {
      uint2 ov;
      ov.x = pk2(oacc[mi2][ni][0] * rl, oacc[mi2][ni][1] * rl);
      ov.y = pk2(oacc[mi2][ni][2] * rl, oacc[mi2][ni][3] * rl);
      *(uint2*)(O + ob + mi2 * 16 + quad * 4) = ov;
    }
  }
}

extern "C" void kernel_launch(void* const* d_in, const int* in_sizes, int n_in,
                              void* d_out, int out_size, void* d_ws, size_t ws_size,
                              hipStream_t stream) {
  const int M = 8192, D = 1024, P = 256, DFF = 512;

  const float* feature_x = (const float*)d_in[0];
  const float* param_x   = (const float*)d_in[1];
  const float* Wq = (const float*)d_in[2];  const float* bq = (const float*)d_in[3];
  const float* Wk = (const float*)d_in[4];  const float* bk = (const float*)d_in[5];
  const float* Wv = (const float*)d_in[6];  const float* bv = (const float*)d_in[7];
  const float* Wo = (const float*)d_in[8];  const float* bo = (const float*)d_in[9];
  const float* alpha1 = (const float*)d_in[10]; const float* beta1 = (const float*)d_in[11];
  const float* alpha2 = (const float*)d_in[12]; const float* beta2 = (const float*)d_in[13];
  const float* W1 = (const float*)d_in[14]; const float* b1 = (const float*)d_in[15];
  const float* W2 = (const float*)d_in[16]; const float* b2 = (const float*)d_in[17];
  const float* Wp = (const float*)d_in[18]; const float* bp = (const float*)d_in[19];

  void* sym = nullptr;
  hipGetSymbolAddress(&sym, HIP_SYMBOL(g_ws));
  u16* s = (u16*)sym;

  u16* xn_b   = s + (size_t)MELEM * 0;
  float* xn_f = (float*)(s + (size_t)MELEM * 1);   // slots 1-2
  u16* qkv_b  = s + (size_t)MELEM * 3;             // slots 3-5 (M x 3072)
  u16* ctx    = s + (size_t)MELEM * 6;
  float* x1_f = (float*)(s + (size_t)MELEM * 7);   // slots 7-8
  u16* x2_b   = s + (size_t)MELEM * 9;
  u16* h1_b   = s + (size_t)MELEM * 10;            // M x 512
  u16* xcp_b  = s + (size_t)MELEM * 11;
  u16* wreg   = s + (size_t)MELEM * 12;
  u16* px_b   = wreg;                              // M x 256
  u16* Wqkvt  = px_b + 2097152;                    // 3072 x 1024
  u16* Wot    = Wqkvt + 3145728;                   // 1024 x 1024
  u16* W1t    = Wot + 1048576;                     // 512 x 1024
  u16* W2t    = W1t + 524288;                      // 1024 x 512
  u16* Wpt    = W2t + 524288;                      // 256 x 1280
  float* bqkv = (float*)(Wpt + 327680);            // 3072 fp32

  float* xout_f = (float*)d_out;
  float* pout_f = xout_f + (size_t)M * D;

  dim3 blk(256);
  // fused weight prep (7 transposes + bias concat + param convert): 1 launch
  prep_kernel<<<13644, blk, 0, stream>>>(Wq, Wk, Wv, Wo, W1, W2, Wp, bq, bk, bv,
                                         param_x, Wqkvt, Wot, W1t, W2t, Wpt,
                                         bqkv, px_b);

  // pipeline
  ln_kernel<<<M, blk, 0, stream>>>(feature_x, alpha1, beta1, xn_b, xn_f);
  gemm_t<128, 128><<<dim3(24, 64), blk, 0, stream>>>(xn_b, nullptr, Wqkvt, bqkv, nullptr,
                                                     nullptr, qkv_b, M, 3072, D, D, 0);
  attn_kernel<<<512, dim3(512), 0, stream>>>(qkv_b, qkv_b + 1024, qkv_b + 2048, ctx, 3072);
  gemm_t<128, 128><<<dim3(8, 64), blk, 0, stream>>>(ctx, nullptr, Wot, bo, xn_f,
                                                    x1_f, nullptr, M, D, D, D, 0);
  ln_kernel<<<M, blk, 0, stream>>>(x1_f, alpha2, beta2, x2_b, nullptr);
  gemm_t<64, 128><<<dim3(4, 128), blk, 0, stream>>>(x2_b, nullptr, W1t, b1, nullptr,
                                                    nullptr, h1_b, M, DFF, D, D, 1);
  gemm_t<128, 128><<<dim3(8, 64), blk, 0, stream>>>(h1_b, nullptr, W2t, b2, x1_f,
                                                    xout_f, xcp_b, M, D, DFF, DFF, 0);
  gemm_t<64, 64><<<dim3(4, 128), blk, 0, stream>>>(xcp_b, px_b, Wpt, bp, nullptr,
                                                   pout_f, nullptr, M, P, D + P, D, 0);
}

// Round 5
// 539.010 us; speedup vs baseline: 1.2245x; 1.0485x over previous
//
#include <hip/hip_runtime.h>
#include <hip/hip_bf16.h>

typedef unsigned short u16;
typedef short short8 __attribute__((ext_vector_type(8)));
typedef float f32x4 __attribute__((ext_vector_type(4)));

// Static device scratch: 13 x MELEM u16 slots.
#define MELEM 8388608u  // 8192*1024
__device__ u16 g_ws[(size_t)MELEM * 13];

__device__ __forceinline__ float b2f(u16 u) {
  union { unsigned int i; float f; } v; v.i = ((unsigned int)u) << 16; return v.f;
}
__device__ __forceinline__ u16 f2b(float f) {
  union { float f; unsigned int i; } v; v.f = f;
  return (u16)((v.i + 0x7FFFu + ((v.i >> 16) & 1u)) >> 16);  // RNE
}
__device__ __forceinline__ unsigned int pk2(float a, float b) {
  union { __hip_bfloat162 h; unsigned int u; } v;
  v.h = __float22bfloat162_rn(make_float2(a, b));  // v_cvt_pk_bf16_f32 (RNE)
  return v.u;
}
__device__ __forceinline__ f32x4 mfma16(short8 a, short8 b, f32x4 c) {
  return __builtin_amdgcn_mfma_f32_16x16x32_bf16(a, b, c, 0, 0, 0);
}

typedef __attribute__((address_space(3))) unsigned int lds_u32;
typedef const __attribute__((address_space(1))) unsigned int glb_u32;
__device__ __forceinline__ void gld16(u16* l, const u16* g) {
  __builtin_amdgcn_global_load_lds((glb_u32*)g, (lds_u32*)l, 16, 0, 0);
}

// exp path: prefer direct exp2 (fold log2e into Q scale, saving one v_mul per score)
#if __has_builtin(__builtin_amdgcn_exp2f)
#define QSCALE 0.18033688011112042f   /* 0.125 * log2(e) */
#define SCLAMP 86.561714f             /* 60 * log2(e) */
#define FEXP(x) __builtin_amdgcn_exp2f(x)
#else
#define QSCALE 0.125f
#define SCLAMP 60.0f
#define FEXP(x) __expf(x)
#endif

// ---- 32x32 fp32->bf16 transpose tile body (shared by all prep transpose jobs)
__device__ __forceinline__ void tr32(const float* __restrict__ W, u16* __restrict__ Wt,
                                     int K, int N, int bx, int by, int tid,
                                     float (*tile)[33]) {
  const int tx = tid & 31, ty = tid >> 5;
#pragma unroll
  for (int i = 0; i < 32; i += 8)
    tile[ty + i][tx] = W[(size_t)(by + ty + i) * N + bx + tx];
  __syncthreads();
#pragma unroll
  for (int i = 0; i < 32; i += 8)
    Wt[(size_t)(bx + ty + i) * K + by + tx] = f2b(tile[tx][ty + i]);
}

// ---- Fused weight prep: 7 transposes + bias concat + param_x convert in ONE launch.
__global__ __launch_bounds__(256) void prep_kernel(
    const float* __restrict__ Wq, const float* __restrict__ Wk,
    const float* __restrict__ Wv, const float* __restrict__ Wo,
    const float* __restrict__ W1, const float* __restrict__ W2,
    const float* __restrict__ Wp,
    const float* __restrict__ bq, const float* __restrict__ bk,
    const float* __restrict__ bv, const float* __restrict__ param_x,
    u16* __restrict__ Wqkvt, u16* __restrict__ Wot, u16* __restrict__ W1t,
    u16* __restrict__ W2t, u16* __restrict__ Wpt,
    float* __restrict__ bqkv, u16* __restrict__ px_b) {
  __shared__ float tile[32][33];
  const int bid = blockIdx.x;
  const int tid = threadIdx.x;
  if (bid < 4096) {
    const int j = bid >> 10, r = bid & 1023;
    const int bx = (r & 31) * 32, by = (r >> 5) * 32;
    const float* src = (j == 0) ? Wq : (j == 1) ? Wk : (j == 2) ? Wv : Wo;
    u16* dst = (j == 3) ? Wot : (Wqkvt + (size_t)j * 1024 * 1024);
    tr32(src, dst, 1024, 1024, bx, by, tid, tile);
  } else if (bid < 4608) {
    const int r = bid - 4096;
    tr32(W1, W1t, 1024, 512, (r & 15) * 32, (r >> 4) * 32, tid, tile);
  } else if (bid < 5120) {
    const int r = bid - 4608;
    tr32(W2, W2t, 512, 1024, (r & 31) * 32, (r >> 5) * 32, tid, tile);
  } else if (bid < 5440) {
    const int r = bid - 5120;
    tr32(Wp, Wpt, 1280, 256, (r & 7) * 32, (r >> 3) * 32, tid, tile);
  } else if (bid < 5452) {
    const int i = (bid - 5440) * 256 + tid;
    bqkv[i] = (i < 1024) ? bq[i] : (i < 2048) ? bk[i - 1024] : bv[i - 2048];
  } else {
    const int i = (bid - 5452) * 256 + tid;
    px_b[i] = f2b(param_x[i]);
  }
}

// ---------------- LayerNorm; fp32 in, bf16(+fp32) out
__global__ __launch_bounds__(256) void ln_kernel(const float* __restrict__ x,
                                                 const float* __restrict__ alpha,
                                                 const float* __restrict__ beta,
                                                 u16* __restrict__ outb,
                                                 float* __restrict__ outf) {
  const int D = 1024;
  const int row = blockIdx.x;
  const int tid = threadIdx.x;
  const float4 u = *(const float4*)(x + (size_t)row * D + tid * 4);
  float s1 = u.x + u.y + u.z + u.w;
  float s2 = u.x * u.x + u.y * u.y + u.z * u.z + u.w * u.w;
#pragma unroll
  for (int off = 32; off >= 1; off >>= 1) {
    s1 += __shfl_xor(s1, off, 64);
    s2 += __shfl_xor(s2, off, 64);
  }
  __shared__ float ws1[4], ws2[4];
  if ((tid & 63) == 0) { ws1[tid >> 6] = s1; ws2[tid >> 6] = s2; }
  __syncthreads();
  s1 = ws1[0] + ws1[1] + ws1[2] + ws1[3];
  s2 = ws2[0] + ws2[1] + ws2[2] + ws2[3];
  const float mean = s1 * (1.0f / 1024.0f);
  const float var = fmaxf((s2 - 1024.0f * mean * mean) * (1.0f / 1023.0f), 0.0f);
  const float inv = 1.0f / (sqrtf(var) + 1e-6f);
  const float4 a = *(const float4*)(alpha + tid * 4);
  const float4 b = *(const float4*)(beta + tid * 4);
  const float o0 = a.x * (u.x - mean) * inv + b.x;
  const float o1 = a.y * (u.y - mean) * inv + b.y;
  const float o2 = a.z * (u.z - mean) * inv + b.z;
  const float o3 = a.w * (u.w - mean) * inv + b.w;
  ushort4 ob; ob.x = f2b(o0); ob.y = f2b(o1); ob.z = f2b(o2); ob.w = f2b(o3);
  *(ushort4*)(outb + (size_t)row * D + tid * 4) = ob;
  if (outf) {
    float4 of; of.x = o0; of.y = o1; of.z = o2; of.w = o3;
    *(float4*)(outf + (size_t)row * D + tid * 4) = of;
  }
}

// ---------------- Templated MFMA GEMM: C = A(MxK) @ Bt(NxK)^T + bias [+resid] [relu]
// TMxTN tile, 4 waves, BK=32, global_load_lds width=16. Single-buffer 2-barrier
// (proven structure; dbuf measured null-to-negative here).
// Cb written with stride ldcb. If Vt_out != nullptr, columns >= 2048 are written
// TRANSPOSED to Vt_out as [b*1024 + (col-2048)][s&2047] (V^T for attention),
// packed ushort4 over the 4 consecutive rows each lane holds.
template<int TM, int TN>
__global__ __launch_bounds__(256) void gemm_t(
    const u16* __restrict__ A, const u16* __restrict__ A2,
    const u16* __restrict__ Bt, const float* __restrict__ bias,
    const float* __restrict__ resid, float* __restrict__ Cf, u16* __restrict__ Cb,
    u16* __restrict__ Vt_out,
    int M, int N, int K, int K1, int relu, int ldcb) {
  __shared__ __align__(16) u16 As[TM * 32];
  __shared__ __align__(16) u16 Bs[TN * 32];
  const int tid = threadIdx.x;
  const int bn = blockIdx.x * TN;
  const int bm = blockIdx.y * TM;
  const int wv = tid >> 6, lane = tid & 63, quad = lane >> 4, l16 = lane & 15;
  constexpr int WN = (TM == 128) ? 64 : TN / 4;
  constexpr int AM = 4, AN = WN / 16;
  const int wm = (TM == 128) ? (wv >> 1) * 64 : 0;
  const int wn = (TM == 128) ? (wv & 1) * 64 : wv * WN;
  const int r0 = tid >> 2;
  const int cc = (tid & 3) * 8;
  f32x4 acc[AM][AN];
#pragma unroll
  for (int i = 0; i < AM; ++i)
#pragma unroll
    for (int j = 0; j < AN; ++j) acc[i][j] = (f32x4){0.f, 0.f, 0.f, 0.f};

  for (int k0 = 0; k0 < K; k0 += 32) {
    const u16* aS; int lda, kk;
    if (A2 != nullptr && k0 >= K1) { aS = A2; lda = K - K1; kk = k0 - K1; }
    else { aS = A; lda = (A2 != nullptr) ? K1 : K; kk = k0; }
#pragma unroll
    for (int i = 0; i < TM / 64; ++i)
      gld16(&As[i * 2048 + tid * 8], aS + (size_t)(bm + i * 64 + r0) * lda + kk + cc);
#pragma unroll
    for (int i = 0; i < TN / 64; ++i)
      gld16(&Bs[i * 2048 + tid * 8], Bt + (size_t)(bn + i * 64 + r0) * K + k0 + cc);
    __syncthreads();
    short8 af[AM], bf[AN];
#pragma unroll
    for (int mi = 0; mi < AM; ++mi)
      af[mi] = *(const short8*)&As[(wm + mi * 16 + l16) * 32 + quad * 8];
#pragma unroll
    for (int ni = 0; ni < AN; ++ni)
      bf[ni] = *(const short8*)&Bs[(wn + ni * 16 + l16) * 32 + quad * 8];
#pragma unroll
    for (int mi = 0; mi < AM; ++mi)
#pragma unroll
      for (int ni = 0; ni < AN; ++ni)
        acc[mi][ni] = mfma16(af[mi], bf[ni], acc[mi][ni]);
    __syncthreads();
  }

#pragma unroll
  for (int ni = 0; ni < AN; ++ni) {
    const int col = bn + wn + ni * 16 + l16;
    const float bb = bias ? bias[col] : 0.0f;
#pragma unroll
    for (int mi = 0; mi < AM; ++mi) {
      if (Vt_out != nullptr && col >= 2048) {
        // V^T write: 4 consecutive seq positions, one dh column -> contiguous ushort4
        const int s0 = bm + wm + mi * 16 + quad * 4;
        const int bb_idx = s0 >> 11;  // batch
        const size_t voff = ((size_t)(bb_idx * 1024 + col - 2048) << 11) + (s0 & 2047);
        ushort4 w;
        w.x = f2b(acc[mi][ni][0] + bb);
        w.y = f2b(acc[mi][ni][1] + bb);
        w.z = f2b(acc[mi][ni][2] + bb);
        w.w = f2b(acc[mi][ni][3] + bb);
        *(ushort4*)(Vt_out + voff) = w;
      } else {
#pragma unroll
        for (int r = 0; r < 4; ++r) {
          const int row = bm + wm + mi * 16 + quad * 4 + r;
          const size_t off = (size_t)row * N + col;
          float v = acc[mi][ni][r] + bb;
          if (resid) v += resid[off];
          if (relu) v = fmaxf(v, 0.0f);
          if (Cf) Cf[off] = v;
          if (Cb) Cb[(size_t)row * ldcb + col] = f2b(v);
        }
      }
    }
  }
}

// ---------------- Flash attention, transposed orientation, single-barrier pipeline.
// 64-key double-buffered tiles; K AND V^T both staged via source-swizzled
// global_load_lds (V supplied pre-transposed by the QKV GEMM epilogue -> no
// scatter, no rotate VALU). Fixed-reference softmax (clamp), exp2-direct.
// Block = (b, h, 256 q rows) with 8 waves; wave = 32 q rows.
// Grid 512, XCD-swizzled so all 8 q-tiles of one (b,h) land on one XCD.
__global__ __launch_bounds__(512) void attn_kernel(
    const u16* __restrict__ Q, const u16* __restrict__ Kb,
    const u16* __restrict__ Vtg, u16* __restrict__ O, int ldq) {
  const int S = 2048, NT = 32;
  __shared__ __align__(16) u16 Ks[2][64][64];   // chunk c of row key at c^(key&7)
  __shared__ __align__(16) u16 Vs[2][64][64];   // [dh][key], chunk c at c^(dh&7)
  __shared__ __align__(16) u16 Pb[8][32][40];   // per-wave P^T: [qrow][key32]
  const int tid = threadIdx.x;
  // XCD-aware bijective swizzle: nwg=512, 8 XCDs, 64 blocks per XCD chunk.
  const int swz = ((blockIdx.x & 7) << 6) | (blockIdx.x >> 3);
  const int qt = swz & 7;
  const int bh = swz >> 3;
  const int b = bh >> 4, h = bh & 15;
  const int wv = tid >> 6, lane = tid & 63, quad = lane >> 4, l16 = lane & 15;
  const size_t brow = (size_t)b * S;
  const size_t hoff = (size_t)h * 64;
  const int q0 = qt * 256 + wv * 32;
  const u16* Vg = Vtg + (((size_t)(b * 1024 + h * 64)) << 11);  // V^T [64 dh][2048]

  // Q B-frags [ni][ks], scaled by QSCALE
  short8 qf[2][2];
#pragma unroll
  for (int ni = 0; ni < 2; ++ni)
#pragma unroll
    for (int ks = 0; ks < 2; ++ks) {
      int4 t = *(const int4*)(Q + (brow + q0 + ni * 16 + l16) * ldq + hoff + ks * 32 + quad * 8);
      const u16* p = (const u16*)&t;
      short8 f;
#pragma unroll
      for (int j = 0; j < 8; ++j) f[j] = (short)f2b(b2f(p[j]) * QSCALE);
      qf[ni][ks] = f;
    }

  f32x4 oacc[4][2];
#pragma unroll
  for (int mi = 0; mi < 4; ++mi)
#pragma unroll
    for (int ni = 0; ni < 2; ++ni) oacc[mi][ni] = (f32x4){0.f, 0.f, 0.f, 0.f};
  float lsum[2] = {0.0f, 0.0f};
  const f32x4 z4 = {0.f, 0.f, 0.f, 0.f};

  // per-thread staging coords (shared by K and V: row = tid>>3, chunk c = swizzled)
  const int srow = tid >> 3;
  const int sc = (tid & 7) ^ (srow & 7);

  // ---- prologue: stage tile 0 into buffer 0 (512 threads: 1 K chunk + 1 V chunk)
  gld16(&Ks[0][0][0] + (size_t)tid * 8, Kb + (brow + srow) * ldq + hoff + sc * 8);
  gld16(&Vs[0][0][0] + (size_t)tid * 8, Vg + ((size_t)srow << 11) + sc * 8);
  __syncthreads();

  for (int t = 0; t < NT; ++t) {
    const int p = t & 1, np = p ^ 1;
    if (t + 1 < NT) {
      const int kbn = (t + 1) * 64;
      gld16(&Ks[np][0][0] + (size_t)tid * 8, Kb + (brow + kbn + srow) * ldq + hoff + sc * 8);
      gld16(&Vs[np][0][0] + (size_t)tid * 8, Vg + ((size_t)srow << 11) + kbn + sc * 8);
    }

    // ---- compute tile t from buffer p
    const u16* ksb = &Ks[p][0][0];
    const u16* vsb = &Vs[p][0][0];
#pragma unroll
    for (int kk = 0; kk < 2; ++kk) {
#pragma unroll
      for (int half = 0; half < 2; ++half) {
        const int m = (kk * 2 + half) * 16 + l16;
        short8 af0 = *(const short8*)(ksb + m * 64 + ((quad ^ (m & 7)) * 8));
        short8 af1 = *(const short8*)(ksb + m * 64 + (((4 + quad) ^ (m & 7)) * 8));
#pragma unroll
        for (int ni = 0; ni < 2; ++ni) {
          f32x4 s = z4;
          s = mfma16(af0, qf[ni][0], s);
          s = mfma16(af1, qf[ni][1], s);
          const float e0 = FEXP(fminf(s[0], SCLAMP));
          const float e1 = FEXP(fminf(s[1], SCLAMP));
          const float e2 = FEXP(fminf(s[2], SCLAMP));
          const float e3 = FEXP(fminf(s[3], SCLAMP));
          lsum[ni] += (e0 + e1) + (e2 + e3);
          uint2 pk;
          pk.x = pk2(e0, e1);
          pk.y = pk2(e2, e3);
          *(uint2*)&Pb[wv][ni * 16 + l16][half * 16 + quad * 4] = pk;
        }
      }
      short8 pf[2];
#pragma unroll
      for (int ni = 0; ni < 2; ++ni)
        pf[ni] = *(const short8*)&Pb[wv][ni * 16 + l16][quad * 8];
      __builtin_amdgcn_s_setprio(1);
#pragma unroll
      for (int mi2 = 0; mi2 < 4; ++mi2) {
        const int dh = mi2 * 16 + l16;
        short8 vf = *(const short8*)(vsb + dh * 64 + (((kk * 4 + quad) ^ (dh & 7)) * 8));
#pragma unroll
        for (int ni = 0; ni < 2; ++ni)
          oacc[mi2][ni] = mfma16(vf, pf[ni], oacc[mi2][ni]);
      }
      __builtin_amdgcn_s_setprio(0);
    }

    if (t + 1 < NT) __syncthreads();
  }

#pragma unroll
  for (int ni = 0; ni < 2; ++ni) {
    lsum[ni] += __shfl_xor(lsum[ni], 16, 64);
    lsum[ni] += __shfl_xor(lsum[ni], 32, 64);
  }
#pragma unroll
  for (int ni = 0; ni < 2; ++ni) {
    const float rl = 1.0f / lsum[ni];
    const size_t ob = (brow + q0 + ni * 16 + l16) * 1024 + hoff;
#pragma unroll
    for (int mi2 = 0; mi2 < 4; ++mi2) {
      uint2 ov;
      ov.x = pk2(oacc[mi2][ni][0] * rl, oacc[mi2][ni][1] * rl);
      ov.y = pk2(oacc[mi2][ni][2] * rl, oacc[mi2][ni][3] * rl);
      *(uint2*)(O + ob + mi2 * 16 + quad * 4) = ov;
    }
  }
}

extern "C" void kernel_launch(void* const* d_in, const int* in_sizes, int n_in,
                              void* d_out, int out_size, void* d_ws, size_t ws_size,
                              hipStream_t stream) {
  const int M = 8192, D = 1024, P = 256, DFF = 512;

  const float* feature_x = (const float*)d_in[0];
  const float* param_x   = (const float*)d_in[1];
  const float* Wq = (const float*)d_in[2];  const float* bq = (const float*)d_in[3];
  const float* Wk = (const float*)d_in[4];  const float* bk = (const float*)d_in[5];
  const float* Wv = (const float*)d_in[6];  const float* bv = (const float*)d_in[7];
  const float* Wo = (const float*)d_in[8];  const float* bo = (const float*)d_in[9];
  const float* alpha1 = (const float*)d_in[10]; const float* beta1 = (const float*)d_in[11];
  const float* alpha2 = (const float*)d_in[12]; const float* beta2 = (const float*)d_in[13];
  const float* W1 = (const float*)d_in[14]; const float* b1 = (const float*)d_in[15];
  const float* W2 = (const float*)d_in[16]; const float* b2 = (const float*)d_in[17];
  const float* Wp = (const float*)d_in[18]; const float* bp = (const float*)d_in[19];

  void* sym = nullptr;
  hipGetSymbolAddress(&sym, HIP_SYMBOL(g_ws));
  u16* s = (u16*)sym;

  u16* xn_b   = s + (size_t)MELEM * 0;
  float* xn_f = (float*)(s + (size_t)MELEM * 1);   // slots 1-2
  u16* qkv_b  = s + (size_t)MELEM * 3;             // slots 3-4 (M x 2048: Q|K)
  u16* vt     = s + (size_t)MELEM * 5;             // slot 5: V^T [b*16+h][64 dh][2048]
  u16* ctx    = s + (size_t)MELEM * 6;
  float* x1_f = (float*)(s + (size_t)MELEM * 7);   // slots 7-8
  u16* x2_b   = s + (size_t)MELEM * 9;
  u16* h1_b   = s + (size_t)MELEM * 10;            // M x 512
  u16* xcp_b  = s + (size_t)MELEM * 11;
  u16* wreg   = s + (size_t)MELEM * 12;
  u16* px_b   = wreg;                              // M x 256
  u16* Wqkvt  = px_b + 2097152;                    // 3072 x 1024
  u16* Wot    = Wqkvt + 3145728;                   // 1024 x 1024
  u16* W1t    = Wot + 1048576;                     // 512 x 1024
  u16* W2t    = W1t + 524288;                      // 1024 x 512
  u16* Wpt    = W2t + 524288;                      // 256 x 1280
  float* bqkv = (float*)(Wpt + 327680);            // 3072 fp32

  float* xout_f = (float*)d_out;
  float* pout_f = xout_f + (size_t)M * D;

  dim3 blk(256);
  // fused weight prep (7 transposes + bias concat + param convert): 1 launch
  prep_kernel<<<13644, blk, 0, stream>>>(Wq, Wk, Wv, Wo, W1, W2, Wp, bq, bk, bv,
                                         param_x, Wqkvt, Wot, W1t, W2t, Wpt,
                                         bqkv, px_b);

  // pipeline
  ln_kernel<<<M, blk, 0, stream>>>(feature_x, alpha1, beta1, xn_b, xn_f);
  gemm_t<128, 128><<<dim3(24, 64), blk, 0, stream>>>(xn_b, nullptr, Wqkvt, bqkv, nullptr,
                                                     nullptr, qkv_b, vt,
                                                     M, 3072, D, D, 0, 2048);
  attn_kernel<<<512, dim3(512), 0, stream>>>(qkv_b, qkv_b + 1024, vt, ctx, 2048);
  gemm_t<128, 128><<<dim3(8, 64), blk, 0, stream>>>(ctx, nullptr, Wot, bo, xn_f,
                                                    x1_f, nullptr, nullptr,
                                                    M, D, D, D, 0, D);
  ln_kernel<<<M, blk, 0, stream>>>(x1_f, alpha2, beta2, x2_b, nullptr);
  gemm_t<64, 128><<<dim3(4, 128), blk, 0, stream>>>(x2_b, nullptr, W1t, b1, nullptr,
                                                    nullptr, h1_b, nullptr,
                                                    M, DFF, D, D, 1, DFF);
  gemm_t<128, 128><<<dim3(8, 64), blk, 0, stream>>>(h1_b, nullptr, W2t, b2, x1_f,
                                                    xout_f, xcp_b, nullptr,
                                                    M, D, DFF, DFF, 0, D);
  gemm_t<64, 64><<<dim3(4, 128), blk, 0, stream>>>(xcp_b, px_b, Wpt, bp, nullptr,
                                                   pout_f, nullptr, nullptr,
                                                   M, P, D + P, D, 0, P);
}

// Round 6
// 454.084 us; speedup vs baseline: 1.4535x; 1.1870x over previous
//
#include <hip/hip_runtime.h>
#include <hip/hip_bf16.h>

typedef unsigned short u16;
typedef short short8 __attribute__((ext_vector_type(8)));
typedef float f32x4 __attribute__((ext_vector_type(4)));

// Static device scratch: 13 x MELEM u16 slots.
#define MELEM 8388608u  // 8192*1024
__device__ u16 g_ws[(size_t)MELEM * 13];

__device__ __forceinline__ float b2f(u16 u) {
  union { unsigned int i; float f; } v; v.i = ((unsigned int)u) << 16; return v.f;
}
__device__ __forceinline__ u16 f2b(float f) {
  union { float f; unsigned int i; } v; v.f = f;
  return (u16)((v.i + 0x7FFFu + ((v.i >> 16) & 1u)) >> 16);  // RNE
}
__device__ __forceinline__ unsigned int pk2(float a, float b) {
  union { __hip_bfloat162 h; unsigned int u; } v;
  v.h = __float22bfloat162_rn(make_float2(a, b));  // v_cvt_pk_bf16_f32 (RNE)
  return v.u;
}
__device__ __forceinline__ f32x4 mfma16(short8 a, short8 b, f32x4 c) {
  return __builtin_amdgcn_mfma_f32_16x16x32_bf16(a, b, c, 0, 0, 0);
}

typedef __attribute__((address_space(3))) unsigned int lds_u32;
typedef const __attribute__((address_space(1))) unsigned int glb_u32;
__device__ __forceinline__ void gld16(u16* l, const u16* g) {
  __builtin_amdgcn_global_load_lds((glb_u32*)g, (lds_u32*)l, 16, 0, 0);
}

// exp path: prefer direct exp2 (fold log2e into Q scale, saving one v_mul per score)
#if __has_builtin(__builtin_amdgcn_exp2f)
#define QSCALE 0.18033688011112042f   /* 0.125 * log2(e) */
#define SCLAMP 86.561714f             /* 60 * log2(e) */
#define FEXP(x) __builtin_amdgcn_exp2f(x)
#else
#define QSCALE 0.125f
#define SCLAMP 60.0f
#define FEXP(x) __expf(x)
#endif

// ---- 32x32 fp32->bf16 transpose tile body (shared by all prep transpose jobs)
__device__ __forceinline__ void tr32(const float* __restrict__ W, u16* __restrict__ Wt,
                                     int K, int N, int bx, int by, int tid,
                                     float (*tile)[33]) {
  const int tx = tid & 31, ty = tid >> 5;
#pragma unroll
  for (int i = 0; i < 32; i += 8)
    tile[ty + i][tx] = W[(size_t)(by + ty + i) * N + bx + tx];
  __syncthreads();
#pragma unroll
  for (int i = 0; i < 32; i += 8)
    Wt[(size_t)(bx + ty + i) * K + by + tx] = f2b(tile[tx][ty + i]);
}

// ---- Fused weight prep: 7 transposes + bias concat + param_x convert in ONE launch.
__global__ __launch_bounds__(256) void prep_kernel(
    const float* __restrict__ Wq, const float* __restrict__ Wk,
    const float* __restrict__ Wv, const float* __restrict__ Wo,
    const float* __restrict__ W1, const float* __restrict__ W2,
    const float* __restrict__ Wp,
    const float* __restrict__ bq, const float* __restrict__ bk,
    const float* __restrict__ bv, const float* __restrict__ param_x,
    u16* __restrict__ Wqkvt, u16* __restrict__ Wot, u16* __restrict__ W1t,
    u16* __restrict__ W2t, u16* __restrict__ Wpt,
    float* __restrict__ bqkv, u16* __restrict__ px_b) {
  __shared__ float tile[32][33];
  const int bid = blockIdx.x;
  const int tid = threadIdx.x;
  if (bid < 4096) {
    const int j = bid >> 10, r = bid & 1023;
    const int bx = (r & 31) * 32, by = (r >> 5) * 32;
    const float* src = (j == 0) ? Wq : (j == 1) ? Wk : (j == 2) ? Wv : Wo;
    u16* dst = (j == 3) ? Wot : (Wqkvt + (size_t)j * 1024 * 1024);
    tr32(src, dst, 1024, 1024, bx, by, tid, tile);
  } else if (bid < 4608) {
    const int r = bid - 4096;
    tr32(W1, W1t, 1024, 512, (r & 15) * 32, (r >> 4) * 32, tid, tile);
  } else if (bid < 5120) {
    const int r = bid - 4608;
    tr32(W2, W2t, 512, 1024, (r & 31) * 32, (r >> 5) * 32, tid, tile);
  } else if (bid < 5440) {
    const int r = bid - 5120;
    tr32(Wp, Wpt, 1280, 256, (r & 7) * 32, (r >> 3) * 32, tid, tile);
  } else if (bid < 5452) {
    const int i = (bid - 5440) * 256 + tid;
    bqkv[i] = (i < 1024) ? bq[i] : (i < 2048) ? bk[i - 1024] : bv[i - 2048];
  } else {
    const int i = (bid - 5452) * 256 + tid;
    px_b[i] = f2b(param_x[i]);
  }
}

// ---------------- LayerNorm; fp32 in, bf16(+fp32) out
__global__ __launch_bounds__(256) void ln_kernel(const float* __restrict__ x,
                                                 const float* __restrict__ alpha,
                                                 const float* __restrict__ beta,
                                                 u16* __restrict__ outb,
                                                 float* __restrict__ outf) {
  const int D = 1024;
  const int row = blockIdx.x;
  const int tid = threadIdx.x;
  const float4 u = *(const float4*)(x + (size_t)row * D + tid * 4);
  float s1 = u.x + u.y + u.z + u.w;
  float s2 = u.x * u.x + u.y * u.y + u.z * u.z + u.w * u.w;
#pragma unroll
  for (int off = 32; off >= 1; off >>= 1) {
    s1 += __shfl_xor(s1, off, 64);
    s2 += __shfl_xor(s2, off, 64);
  }
  __shared__ float ws1[4], ws2[4];
  if ((tid & 63) == 0) { ws1[tid >> 6] = s1; ws2[tid >> 6] = s2; }
  __syncthreads();
  s1 = ws1[0] + ws1[1] + ws1[2] + ws1[3];
  s2 = ws2[0] + ws2[1] + ws2[2] + ws2[3];
  const float mean = s1 * (1.0f / 1024.0f);
  const float var = fmaxf((s2 - 1024.0f * mean * mean) * (1.0f / 1023.0f), 0.0f);
  const float inv = 1.0f / (sqrtf(var) + 1e-6f);
  const float4 a = *(const float4*)(alpha + tid * 4);
  const float4 b = *(const float4*)(beta + tid * 4);
  const float o0 = a.x * (u.x - mean) * inv + b.x;
  const float o1 = a.y * (u.y - mean) * inv + b.y;
  const float o2 = a.z * (u.z - mean) * inv + b.z;
  const float o3 = a.w * (u.w - mean) * inv + b.w;
  ushort4 ob; ob.x = f2b(o0); ob.y = f2b(o1); ob.z = f2b(o2); ob.w = f2b(o3);
  *(ushort4*)(outb + (size_t)row * D + tid * 4) = ob;
  if (outf) {
    float4 of; of.x = o0; of.y = o1; of.z = o2; of.w = o3;
    *(float4*)(outf + (size_t)row * D + tid * 4) = of;
  }
}

// ---------------- Templated MFMA GEMM: C = A(MxK) @ Bt(NxK)^T + bias [+resid] [relu]
// TMxTN tile, 4 waves, BK=64 (2x MFMA per barrier event vs BK=32), global_load_lds
// width=16 with BOTH-SIDES XOR chunk swizzle (rule #21; same pattern as attn Ks):
// LDS[row][cb] holds source chunk cb^(row&7); reads are 2-lanes/bank conflict-free.
// XCD-aware bijective block swizzle when gridDim.x%8==0: each XCD owns an N-strip
// (B-panel L2-resident) with same-M N-tiles consecutive (A-tile L2 hit).
// Cb written with stride ldcb. If Vt_out != nullptr, columns >= 2048 are written
// TRANSPOSED to Vt_out as [b*1024 + (col-2048)][s&2047] (V^T for attention).
template<int TM, int TN>
__global__ __launch_bounds__(256) void gemm_t(
    const u16* __restrict__ A, const u16* __restrict__ A2,
    const u16* __restrict__ Bt, const float* __restrict__ bias,
    const float* __restrict__ resid, float* __restrict__ Cf, u16* __restrict__ Cb,
    u16* __restrict__ Vt_out,
    int M, int N, int K, int K1, int relu, int ldcb) {
  __shared__ __align__(16) u16 As[TM * 64];
  __shared__ __align__(16) u16 Bs[TN * 64];
  const int tid = threadIdx.x;
  const int nx = gridDim.x;
  int bxi, byi;
  if ((nx & 7) == 0) {
    const int bid = blockIdx.y * nx + blockIdx.x;
    const int xcd = bid & 7, idx = bid >> 3, nxl = nx >> 3;
    bxi = xcd * nxl + idx % nxl;
    byi = idx / nxl;
  } else { bxi = blockIdx.x; byi = blockIdx.y; }
  const int bn = bxi * TN;
  const int bm = byi * TM;
  const int wv = tid >> 6, lane = tid & 63, quad = lane >> 4, l16 = lane & 15;
  const int lx = l16 & 7;
  constexpr int WN = (TM == 128) ? 64 : TN / 4;
  constexpr int AM = 4, AN = WN / 16;
  const int wm = (TM == 128) ? (wv >> 1) * 64 : 0;
  const int wn = (TM == 128) ? (wv & 1) * 64 : wv * WN;
  f32x4 acc[AM][AN];
#pragma unroll
  for (int i = 0; i < AM; ++i)
#pragma unroll
    for (int j = 0; j < AN; ++j) acc[i][j] = (f32x4){0.f, 0.f, 0.f, 0.f};

  for (int k0 = 0; k0 < K; k0 += 64) {
    const u16* aS; int lda, kk;
    if (A2 != nullptr && k0 >= K1) { aS = A2; lda = K - K1; kk = k0 - K1; }
    else { aS = A; lda = (A2 != nullptr) ? K1 : K; kk = k0; }
    // stage A: TM*8 chunks of 16B; linear LDS dest, source chunk cb^(row&7)
#pragma unroll
    for (int i = 0; i < TM / 32; ++i) {
      const int s = i * 256 + tid, row = s >> 3, cb = s & 7;
      gld16(&As[s * 8], aS + (size_t)(bm + row) * lda + kk + ((cb ^ (row & 7)) * 8));
    }
#pragma unroll
    for (int i = 0; i < TN / 32; ++i) {
      const int s = i * 256 + tid, row = s >> 3, cb = s & 7;
      gld16(&Bs[s * 8], Bt + (size_t)(bn + row) * K + k0 + ((cb ^ (row & 7)) * 8));
    }
    __syncthreads();
#pragma unroll
    for (int kkh = 0; kkh < 2; ++kkh) {
      const int jq = ((kkh << 2) | quad) ^ lx;  // swizzled chunk for this lane
      short8 af[AM], bf[AN];
#pragma unroll
      for (int mi = 0; mi < AM; ++mi)
        af[mi] = *(const short8*)&As[(wm + mi * 16 + l16) * 64 + jq * 8];
#pragma unroll
      for (int ni = 0; ni < AN; ++ni)
        bf[ni] = *(const short8*)&Bs[(wn + ni * 16 + l16) * 64 + jq * 8];
#pragma unroll
      for (int mi = 0; mi < AM; ++mi)
#pragma unroll
        for (int ni = 0; ni < AN; ++ni)
          acc[mi][ni] = mfma16(af[mi], bf[ni], acc[mi][ni]);
    }
    __syncthreads();
  }

#pragma unroll
  for (int ni = 0; ni < AN; ++ni) {
    const int col = bn + wn + ni * 16 + l16;
    const float bb = bias ? bias[col] : 0.0f;
#pragma unroll
    for (int mi = 0; mi < AM; ++mi) {
      if (Vt_out != nullptr && col >= 2048) {
        // V^T write: 4 consecutive seq positions, one dh column -> contiguous ushort4
        const int s0 = bm + wm + mi * 16 + quad * 4;
        const int bb_idx = s0 >> 11;  // batch
        const size_t voff = ((size_t)(bb_idx * 1024 + col - 2048) << 11) + (s0 & 2047);
        ushort4 w;
        w.x = f2b(acc[mi][ni][0] + bb);
        w.y = f2b(acc[mi][ni][1] + bb);
        w.z = f2b(acc[mi][ni][2] + bb);
        w.w = f2b(acc[mi][ni][3] + bb);
        *(ushort4*)(Vt_out + voff) = w;
      } else {
#pragma unroll
        for (int r = 0; r < 4; ++r) {
          const int row = bm + wm + mi * 16 + quad * 4 + r;
          const size_t off = (size_t)row * N + col;
          float v = acc[mi][ni][r] + bb;
          if (resid) v += resid[off];
          if (relu) v = fmaxf(v, 0.0f);
          if (Cf) Cf[off] = v;
          if (Cb) Cb[(size_t)row * ldcb + col] = f2b(v);
        }
      }
    }
  }
}

// ---------------- Flash attention, transposed orientation, single-barrier pipeline.
// 64-key double-buffered tiles; K AND V^T both staged via source-swizzled
// global_load_lds (V supplied pre-transposed by the QKV GEMM epilogue -> no
// scatter, no rotate VALU). Fixed-reference softmax (clamp), exp2-direct.
// Block = (b, h, 256 q rows) with 8 waves; wave = 32 q rows.
// Grid 512, XCD-swizzled so all 8 q-tiles of one (b,h) land on one XCD.
__global__ __launch_bounds__(512) void attn_kernel(
    const u16* __restrict__ Q, const u16* __restrict__ Kb,
    const u16* __restrict__ Vtg, u16* __restrict__ O, int ldq) {
  const int S = 2048, NT = 32;
  __shared__ __align__(16) u16 Ks[2][64][64];   // chunk c of row key at c^(key&7)
  __shared__ __align__(16) u16 Vs[2][64][64];   // [dh][key], chunk c at c^(dh&7)
  __shared__ __align__(16) u16 Pb[8][32][40];   // per-wave P^T: [qrow][key32]
  const int tid = threadIdx.x;
  // XCD-aware bijective swizzle: nwg=512, 8 XCDs, 64 blocks per XCD chunk.
  const int swz = ((blockIdx.x & 7) << 6) | (blockIdx.x >> 3);
  const int qt = swz & 7;
  const int bh = swz >> 3;
  const int b = bh >> 4, h = bh & 15;
  const int wv = tid >> 6, lane = tid & 63, quad = lane >> 4, l16 = lane & 15;
  const size_t brow = (size_t)b * S;
  const size_t hoff = (size_t)h * 64;
  const int q0 = qt * 256 + wv * 32;
  const u16* Vg = Vtg + (((size_t)(b * 1024 + h * 64)) << 11);  // V^T [64 dh][2048]

  // Q B-frags [ni][ks], scaled by QSCALE
  short8 qf[2][2];
#pragma unroll
  for (int ni = 0; ni < 2; ++ni)
#pragma unroll
    for (int ks = 0; ks < 2; ++ks) {
      int4 t = *(const int4*)(Q + (brow + q0 + ni * 16 + l16) * ldq + hoff + ks * 32 + quad * 8);
      const u16* p = (const u16*)&t;
      short8 f;
#pragma unroll
      for (int j = 0; j < 8; ++j) f[j] = (short)f2b(b2f(p[j]) * QSCALE);
      qf[ni][ks] = f;
    }

  f32x4 oacc[4][2];
#pragma unroll
  for (int mi = 0; mi < 4; ++mi)
#pragma unroll
    for (int ni = 0; ni < 2; ++ni) oacc[mi][ni] = (f32x4){0.f, 0.f, 0.f, 0.f};
  float lsum[2] = {0.0f, 0.0f};
  const f32x4 z4 = {0.f, 0.f, 0.f, 0.f};

  // per-thread staging coords (shared by K and V: row = tid>>3, chunk c = swizzled)
  const int srow = tid >> 3;
  const int sc = (tid & 7) ^ (srow & 7);

  // ---- prologue: stage tile 0 into buffer 0 (512 threads: 1 K chunk + 1 V chunk)
  gld16(&Ks[0][0][0] + (size_t)tid * 8, Kb + (brow + srow) * ldq + hoff + sc * 8);
  gld16(&Vs[0][0][0] + (size_t)tid * 8, Vg + ((size_t)srow << 11) + sc * 8);
  __syncthreads();

  for (int t = 0; t < NT; ++t) {
    const int p = t & 1, np = p ^ 1;
    if (t + 1 < NT) {
      const int kbn = (t + 1) * 64;
      gld16(&Ks[np][0][0] + (size_t)tid * 8, Kb + (brow + kbn + srow) * ldq + hoff + sc * 8);
      gld16(&Vs[np][0][0] + (size_t)tid * 8, Vg + ((size_t)srow << 11) + kbn + sc * 8);
    }

    // ---- compute tile t from buffer p
    const u16* ksb = &Ks[p][0][0];
    const u16* vsb = &Vs[p][0][0];
#pragma unroll
    for (int kk = 0; kk < 2; ++kk) {
#pragma unroll
      for (int half = 0; half < 2; ++half) {
        const int m = (kk * 2 + half) * 16 + l16;
        short8 af0 = *(const short8*)(ksb + m * 64 + ((quad ^ (m & 7)) * 8));
        short8 af1 = *(const short8*)(ksb + m * 64 + (((4 + quad) ^ (m & 7)) * 8));
#pragma unroll
        for (int ni = 0; ni < 2; ++ni) {
          f32x4 s = z4;
          s = mfma16(af0, qf[ni][0], s);
          s = mfma16(af1, qf[ni][1], s);
          const float e0 = FEXP(fminf(s[0], SCLAMP));
          const float e1 = FEXP(fminf(s[1], SCLAMP));
          const float e2 = FEXP(fminf(s[2], SCLAMP));
          const float e3 = FEXP(fminf(s[3], SCLAMP));
          lsum[ni] += (e0 + e1) + (e2 + e3);
          uint2 pk;
          pk.x = pk2(e0, e1);
          pk.y = pk2(e2, e3);
          *(uint2*)&Pb[wv][ni * 16 + l16][half * 16 + quad * 4] = pk;
        }
      }
      short8 pf[2];
#pragma unroll
      for (int ni = 0; ni < 2; ++ni)
        pf[ni] = *(const short8*)&Pb[wv][ni * 16 + l16][quad * 8];
      __builtin_amdgcn_s_setprio(1);
#pragma unroll
      for (int mi2 = 0; mi2 < 4; ++mi2) {
        const int dh = mi2 * 16 + l16;
        short8 vf = *(const short8*)(vsb + dh * 64 + (((kk * 4 + quad) ^ (dh & 7)) * 8));
#pragma unroll
        for (int ni = 0; ni < 2; ++ni)
          oacc[mi2][ni] = mfma16(vf, pf[ni], oacc[mi2][ni]);
      }
      __builtin_amdgcn_s_setprio(0);
    }

    if (t + 1 < NT) __syncthreads();
  }

#pragma unroll
  for (int ni = 0; ni < 2; ++ni) {
    lsum[ni] += __shfl_xor(lsum[ni], 16, 64);
    lsum[ni] += __shfl_xor(lsum[ni], 32, 64);
  }
#pragma unroll
  for (int ni = 0; ni < 2; ++ni) {
    const float rl = 1.0f / lsum[ni];
    const size_t ob = (brow + q0 + ni * 16 + l16) * 1024 + hoff;
#pragma unroll
    for (int mi2 = 0; mi2 < 4; ++mi2) {
      uint2 ov;
      ov.x = pk2(oacc[mi2][ni][0] * rl, oacc[mi2][ni][1] * rl);
      ov.y = pk2(oacc[mi2][ni][2] * rl, oacc[mi2][ni][3] * rl);
      *(uint2*)(O + ob + mi2 * 16 + quad * 4) = ov;
    }
  }
}

extern "C" void kernel_launch(void* const* d_in, const int* in_sizes, int n_in,
                              void* d_out, int out_size, void* d_ws, size_t ws_size,
                              hipStream_t stream) {
  const int M = 8192, D = 1024, P = 256, DFF = 512;

  const float* feature_x = (const float*)d_in[0];
  const float* param_x   = (const float*)d_in[1];
  const float* Wq = (const float*)d_in[2];  const float* bq = (const float*)d_in[3];
  const float* Wk = (const float*)d_in[4];  const float* bk = (const float*)d_in[5];
  const float* Wv = (const float*)d_in[6];  const float* bv = (const float*)d_in[7];
  const float* Wo = (const float*)d_in[8];  const float* bo = (const float*)d_in[9];
  const float* alpha1 = (const float*)d_in[10]; const float* beta1 = (const float*)d_in[11];
  const float* alpha2 = (const float*)d_in[12]; const float* beta2 = (const float*)d_in[13];
  const float* W1 = (const float*)d_in[14]; const float* b1 = (const float*)d_in[15];
  const float* W2 = (const float*)d_in[16]; const float* b2 = (const float*)d_in[17];
  const float* Wp = (const float*)d_in[18]; const float* bp = (const float*)d_in[19];

  void* sym = nullptr;
  hipGetSymbolAddress(&sym, HIP_SYMBOL(g_ws));
  u16* s = (u16*)sym;

  u16* xn_b   = s + (size_t)MELEM * 0;
  float* xn_f = (float*)(s + (size_t)MELEM * 1);   // slots 1-2
  u16* qkv_b  = s + (size_t)MELEM * 3;             // slots 3-4 (M x 2048: Q|K)
  u16* vt     = s + (size_t)MELEM * 5;             // slot 5: V^T [b*16+h][64 dh][2048]
  u16* ctx    = s + (size_t)MELEM * 6;
  float* x1_f = (float*)(s + (size_t)MELEM * 7);   // slots 7-8
  u16* x2_b   = s + (size_t)MELEM * 9;
  u16* h1_b   = s + (size_t)MELEM * 10;            // M x 512
  u16* xcp_b  = s + (size_t)MELEM * 11;
  u16* wreg   = s + (size_t)MELEM * 12;
  u16* px_b   = wreg;                              // M x 256
  u16* Wqkvt  = px_b + 2097152;                    // 3072 x 1024
  u16* Wot    = Wqkvt + 3145728;                   // 1024 x 1024
  u16* W1t    = Wot + 1048576;                     // 512 x 1024
  u16* W2t    = W1t + 524288;                      // 1024 x 512
  u16* Wpt    = W2t + 524288;                      // 256 x 1280
  float* bqkv = (float*)(Wpt + 327680);            // 3072 fp32

  float* xout_f = (float*)d_out;
  float* pout_f = xout_f + (size_t)M * D;

  dim3 blk(256);
  // fused weight prep (7 transposes + bias concat + param convert): 1 launch
  prep_kernel<<<13644, blk, 0, stream>>>(Wq, Wk, Wv, Wo, W1, W2, Wp, bq, bk, bv,
                                         param_x, Wqkvt, Wot, W1t, W2t, Wpt,
                                         bqkv, px_b);

  // pipeline
  ln_kernel<<<M, blk, 0, stream>>>(feature_x, alpha1, beta1, xn_b, xn_f);
  gemm_t<128, 128><<<dim3(24, 64), blk, 0, stream>>>(xn_b, nullptr, Wqkvt, bqkv, nullptr,
                                                     nullptr, qkv_b, vt,
                                                     M, 3072, D, D, 0, 2048);
  attn_kernel<<<512, dim3(512), 0, stream>>>(qkv_b, qkv_b + 1024, vt, ctx, 2048);
  gemm_t<128, 128><<<dim3(8, 64), blk, 0, stream>>>(ctx, nullptr, Wot, bo, xn_f,
                                                    x1_f, nullptr, nullptr,
                                                    M, D, D, D, 0, D);
  ln_kernel<<<M, blk, 0, stream>>>(x1_f, alpha2, beta2, x2_b, nullptr);
  gemm_t<64, 128><<<dim3(4, 128), blk, 0, stream>>>(x2_b, nullptr, W1t, b1, nullptr,
                                                    nullptr, h1_b, nullptr,
                                                    M, DFF, D, D, 1, DFF);
  gemm_t<128, 128><<<dim3(8, 64), blk, 0, stream>>>(h1_b, nullptr, W2t, b2, x1_f,
                                                    xout_f, xcp_b, nullptr,
                                                    M, D, DFF, DFF, 0, D);
  gemm_t<64, 64><<<dim3(4, 128), blk, 0, stream>>>(xcp_b, px_b, Wpt, bp, nullptr,
                                                   pout_f, nullptr, nullptr,
                                                   M, P, D + P, D, 0, P);
}